// Round 9
// baseline (397.637 us; speedup 1.0000x reference)
//
#include <hip/hip_runtime.h>
#include <hip/hip_bf16.h>

// MoChA. Round 9: (1) alpha_scan split across 4 waves per (b,h) (k-split,
// LDS cross-wave prefix, 4-deep prefetch) -> 4x memory-level parallelism;
// (2) beta_kernel one block per (b,q), all hm x hc in-block (alpha read once).
// B=8, Q=128, K=1024, D=512, HM=HC=4, CHUNK=4.

#define NEG_INF (-3.402823466e38f)
#define EPS_MOCHA 1e-6f
#define INV_SCALE 0.04419417382415922f  // 1/sqrt(512)

typedef _Float16 half8 __attribute__((ext_vector_type(8)));
typedef _Float16 half4v __attribute__((ext_vector_type(4)));
typedef float f32x4 __attribute__((ext_vector_type(4)));

// ---------------------------------------------------------------------------
// cvt: fp32 -> fp16, vectorized x4. Grid exactly n/4/256 blocks.
// ---------------------------------------------------------------------------
__global__ __launch_bounds__(256) void cvt_f32_f16(
    const float* __restrict__ in, _Float16* __restrict__ out)
{
    const size_t i = (size_t)blockIdx.x * 256 + threadIdx.x;
    float4 v = *(const float4*)(in + i * 4);
    half4v h = {(_Float16)v.x, (_Float16)v.y, (_Float16)v.z, (_Float16)v.w};
    *(half4v*)(out + i * 4) = h;
}

// ---------------------------------------------------------------------------
// pack_weights: Wt[n][k] = (fp16) W[k][n] for up to 5 weights (grid z).
// ---------------------------------------------------------------------------
__global__ __launch_bounds__(256) void pack_weights(
    const float* __restrict__ Wa, const float* __restrict__ Wb,
    const float* __restrict__ Wc, const float* __restrict__ Wd,
    const float* __restrict__ We, _Float16* __restrict__ out)
{
    const int z = blockIdx.z;
    const float* W = (z == 0) ? Wa : (z == 1) ? Wb : (z == 2) ? Wc
                   : (z == 3) ? Wd : We;
    _Float16* O = out + (size_t)z * 512 * 512;
    const int n0 = blockIdx.x * 64, k0 = blockIdx.y * 64;
    __shared__ float T[64][65];
    const int t = threadIdx.x;
    const int rr = t >> 4, cc = (t & 15) * 4;
#pragma unroll
    for (int r = 0; r < 4; ++r) {
        int k = r * 16 + rr;
        float4 v = *(const float4*)(W + (size_t)(k0 + k) * 512 + n0 + cc);
        T[k][cc + 0] = v.x; T[k][cc + 1] = v.y;
        T[k][cc + 2] = v.z; T[k][cc + 3] = v.w;
    }
    __syncthreads();
    const int nn = t >> 2, kc = (t & 3) * 16;
    _Float16 tmp[16];
#pragma unroll
    for (int i = 0; i < 16; ++i) tmp[i] = (_Float16)T[kc + i][nn];
    _Float16* Op = O + (size_t)(n0 + nn) * 512 + k0 + kc;
    *(half8*)(Op)     = *(half8*)&tmp[0];
    *(half8*)(Op + 8) = *(half8*)&tmp[8];
}

// ---------------------------------------------------------------------------
// MFMA fragment helpers (16x16x32 f16, fp32 acc); k-contiguous rows stride 512.
// ---------------------------------------------------------------------------
__device__ __forceinline__ void load_frags(
    const _Float16* Ap, const _Float16* Bp, int kk, half8 a[4], half8 b[4])
{
#pragma unroll
    for (int t = 0; t < 4; ++t) {
        a[t] = *(const half8*)(Ap + (size_t)t * 16 * 512 + kk);
        b[t] = *(const half8*)(Bp + (size_t)t * 16 * 512 + kk);
    }
}

__device__ __forceinline__ void mfma_step(half8 a[4], half8 b[4], f32x4 acc[4][4])
{
#pragma unroll
    for (int mt = 0; mt < 4; ++mt)
#pragma unroll
        for (int nt = 0; nt < 4; ++nt)
            acc[mt][nt] = __builtin_amdgcn_mfma_f32_16x16x32_f16(
                a[mt], b[nt], acc[mt][nt], 0, 0, 0);
}

// ---------------------------------------------------------------------------
// MFMA projection GEMM: C[m][n] = sum_k A16[m][k]*Wt[n][k] + bias.
// Block 256 = 2x2 waves, tile 128x128, wave 64x64, K=512, 3-deep pipeline.
// f16_mask bit g: C stored fp16.
// ---------------------------------------------------------------------------
__global__ __launch_bounds__(256) void mfma_proj(
    const _Float16* __restrict__ A16, const _Float16* __restrict__ Wt_base,
    const float* __restrict__ bias0, void* __restrict__ C0,
    const float* __restrict__ bias1, void* __restrict__ C1,
    const float* __restrict__ bias2, void* __restrict__ C2,
    int f16_mask)
{
    const int tid = threadIdx.x;
    const int lane = tid & 63, wave = tid >> 6;
    const int wm = wave >> 1, wn = wave & 1;
    const int col = lane & 15, quad = lane >> 4;
    const int g = blockIdx.y >> 2, nt128 = blockIdx.y & 3;
    const _Float16* Wt = Wt_base + (size_t)g * 262144;
    const float* bias = (g == 0) ? bias0 : (g == 1) ? bias1 : bias2;
    void*        Cv   = (g == 0) ? C0    : (g == 1) ? C1    : C2;
    const int f16o = (f16_mask >> g) & 1;
    const int m0 = blockIdx.x * 128, n0 = nt128 * 128;

    const _Float16* Ap = A16 + (size_t)(m0 + wm * 64 + col) * 512 + quad * 8;
    const _Float16* Bp = Wt  + (size_t)(n0 + wn * 64 + col) * 512 + quad * 8;

    f32x4 acc[4][4];
#pragma unroll
    for (int mt = 0; mt < 4; ++mt)
#pragma unroll
        for (int nt = 0; nt < 4; ++nt) acc[mt][nt] = (f32x4)0.f;

    half8 ab[3][4], bb[3][4];
    load_frags(Ap, Bp, 0, ab[0], bb[0]);
    load_frags(Ap, Bp, 32, ab[1], bb[1]);
#pragma unroll
    for (int ks = 0; ks < 16; ++ks) {
        const int cur = ks % 3, nxt = (ks + 2) % 3;
        if (ks + 2 < 16)
            load_frags(Ap, Bp, (ks + 2) * 32, ab[nxt], bb[nxt]);
        mfma_step(ab[cur], bb[cur], acc);
    }

    float bnt[4];
#pragma unroll
    for (int nt = 0; nt < 4; ++nt)
        bnt[nt] = bias[n0 + wn * 64 + nt * 16 + col];
#pragma unroll
    for (int mt = 0; mt < 4; ++mt) {
        const int rowb = m0 + wm * 64 + mt * 16 + quad * 4;
#pragma unroll
        for (int nt = 0; nt < 4; ++nt) {
            const int cc = n0 + wn * 64 + nt * 16 + col;
#pragma unroll
            for (int r = 0; r < 4; ++r) {
                float v = acc[mt][nt][r] + bnt[nt];
                if (f16o)
                    ((_Float16*)Cv)[(size_t)(rowb + r) * 512 + cc] = (_Float16)v;
                else
                    ((float*)Cv)[(size_t)(rowb + r) * 512 + cc] = v;
            }
        }
    }
}

// ---------------------------------------------------------------------------
// Energy via MFMA: out[b,h,q,k] = dot_128(Q16, K16) * INV_SCALE (+ r), masked.
// 3-deep pipeline over 4 K-steps. Grid: (kt=8, h=4, b=8).
// ---------------------------------------------------------------------------
__global__ __launch_bounds__(256) void energy_mfma(
    const _Float16* __restrict__ Qp, const _Float16* __restrict__ Kp,
    const int* __restrict__ mask, float* __restrict__ out,
    const float* __restrict__ r_ptr, int use_r)
{
    const int tid = threadIdx.x;
    const int lane = tid & 63, wave = tid >> 6;
    const int wm = wave >> 1, wn = wave & 1;
    const int col = lane & 15, quad = lane >> 4;
    const int kt0 = blockIdx.x * 128;
    const int h = blockIdx.y, b = blockIdx.z;

    const _Float16* Ap = Qp + (size_t)(b * 128 + wm * 64 + col) * 512 + h * 128 + quad * 8;
    const _Float16* Bp = Kp + (size_t)(b * 1024 + kt0 + wn * 64 + col) * 512 + h * 128 + quad * 8;

    f32x4 acc[4][4];
#pragma unroll
    for (int mt = 0; mt < 4; ++mt)
#pragma unroll
        for (int nt = 0; nt < 4; ++nt) acc[mt][nt] = (f32x4)0.f;

    half8 ab[3][4], bb[3][4];
    load_frags(Ap, Bp, 0, ab[0], bb[0]);
    load_frags(Ap, Bp, 32, ab[1], bb[1]);
#pragma unroll
    for (int ks = 0; ks < 4; ++ks) {
        const int cur = ks % 3, nxt = (ks + 2) % 3;
        if (ks + 2 < 4)
            load_frags(Ap, Bp, (ks + 2) * 32, ab[nxt], bb[nxt]);
        mfma_step(ab[cur], bb[cur], acc);
    }

    const float rv = use_r ? r_ptr[0] : 0.f;
#pragma unroll
    for (int mt = 0; mt < 4; ++mt) {
        const int qb = wm * 64 + mt * 16 + quad * 4;
#pragma unroll
        for (int nt = 0; nt < 4; ++nt) {
            const int kc = kt0 + wn * 64 + nt * 16 + col;
#pragma unroll
            for (int r = 0; r < 4; ++r) {
                const int q = qb + r;
                float v = acc[mt][nt][r] * INV_SCALE + rv;
                int mv = mask[((size_t)b * 128 + q) * 1024 + kc];
                out[(((size_t)b * 4 + h) * 128 + q) * 1024 + kc] = mv ? v : NEG_INF;
            }
        }
    }
}

// ---------------------------------------------------------------------------
// alpha_pre: parallel part of the monotonic recurrence (one wave per row,
// 4096 rows). p=sigmoid(e); cp=exp(excl_cumsum(log(max(1-p,eps))));
// pcp=p*cp (in-place over e_mono); invcp=1/max(cp,eps).
// ---------------------------------------------------------------------------
__global__ __launch_bounds__(256) void alpha_pre(
    const float* __restrict__ e_mono, float* __restrict__ pcp,
    float* __restrict__ invcp)
{
    const int tid = threadIdx.x;
    const int lane = tid & 63;
    const int row = blockIdx.x * 4 + (tid >> 6);
    const float* E = e_mono + (size_t)row * 1024 + lane * 16;

    float e[16];
    *(float4*)&e[0]  = *(const float4*)(E);
    *(float4*)&e[4]  = *(const float4*)(E + 4);
    *(float4*)&e[8]  = *(const float4*)(E + 8);
    *(float4*)&e[12] = *(const float4*)(E + 12);

    float p[16], l[16];
#pragma unroll
    for (int i = 0; i < 16; ++i) {
        p[i] = 1.f / (1.f + expf(-e[i]));
        l[i] = logf(fmaxf(1.f - p[i], EPS_MOCHA));
    }
    float incl[16];
    incl[0] = l[0];
#pragma unroll
    for (int i = 1; i < 16; ++i) incl[i] = incl[i - 1] + l[i];
    float total = incl[15];
    float x = total;
#pragma unroll
    for (int off = 1; off < 64; off <<= 1) {
        float y = __shfl_up(x, off, 64);
        if (lane >= off) x += y;
    }
    float base = x - total;  // exclusive across lanes

    float o1[16], o2[16];
#pragma unroll
    for (int i = 0; i < 16; ++i) {
        float cl = base + (i ? incl[i - 1] : 0.f);
        float cp = expf(cl);
        o1[i] = p[i] * cp;
        o2[i] = 1.f / fmaxf(cp, EPS_MOCHA);
    }
    float* P = pcp + (size_t)row * 1024 + lane * 16;
    float* I = invcp + (size_t)row * 1024 + lane * 16;
    *(float4*)(P)      = *(float4*)&o1[0];
    *(float4*)(P + 4)  = *(float4*)&o1[4];
    *(float4*)(P + 8)  = *(float4*)&o1[8];
    *(float4*)(P + 12) = *(float4*)&o1[12];
    *(float4*)(I)      = *(float4*)&o2[0];
    *(float4*)(I + 4)  = *(float4*)&o2[4];
    *(float4*)(I + 8)  = *(float4*)&o2[8];
    *(float4*)(I + 12) = *(float4*)&o2[12];
}

// ---------------------------------------------------------------------------
// alpha_scan: 4 waves per (b,h), k-split (4 k per lane), 4-deep prefetch.
// Cross-wave prefix via double-buffered LDS totals, one barrier per q-step.
// Per q: aw = pcp * inclusive_cumsum_k(aw_prev * invcp).
// ---------------------------------------------------------------------------
__global__ __launch_bounds__(256) void alpha_scan(
    const float* __restrict__ pcp, const float* __restrict__ invcp,
    float* __restrict__ alpha)
{
    __shared__ float wtot[2][4];
    const int tid = threadIdx.x;
    const int lane = tid & 63, w = tid >> 6;
    const int bh = blockIdx.x;
    const float* P = pcp + (size_t)bh * 131072 + tid * 4;
    const float* I = invcp + (size_t)bh * 131072 + tid * 4;
    float* A = alpha + (size_t)bh * 131072 + tid * 4;

    float bp[4][4], bi[4][4];
#pragma unroll
    for (int s = 0; s < 4; ++s) {
        *(float4*)&bp[s][0] = *(const float4*)(P + (size_t)s * 1024);
        *(float4*)&bi[s][0] = *(const float4*)(I + (size_t)s * 1024);
    }

    float aw[4] = {0.f, 0.f, 0.f, 0.f};
    if (tid == 0) aw[0] = 1.f;

    for (int q = 0; q < 128; ++q) {
        const int s = q & 3;
        float pc[4], ic[4];
#pragma unroll
        for (int i = 0; i < 4; ++i) { pc[i] = bp[s][i]; ic[i] = bi[s][i]; }
        if (q + 4 < 128) {  // refill slot s for q+4 (issues before the chain)
            *(float4*)&bp[s][0] = *(const float4*)(P + (size_t)(q + 4) * 1024);
            *(float4*)&bi[s][0] = *(const float4*)(I + (size_t)(q + 4) * 1024);
        }

        // per-lane inclusive prefix of t = aw*ic
        float t0 = aw[0] * ic[0];
        float t1 = t0 + aw[1] * ic[1];
        float t2 = t1 + aw[2] * ic[2];
        float t3 = t2 + aw[3] * ic[3];
        // wave inclusive scan of lane totals
        float x = t3;
#pragma unroll
        for (int off = 1; off < 64; off <<= 1) {
            float y = __shfl_up(x, off, 64);
            if (lane >= off) x += y;
        }
        if (lane == 63) wtot[q & 1][w] = x;
        __syncthreads();
        float woff = 0.f;
#pragma unroll
        for (int ww = 0; ww < 3; ++ww)
            if (ww < w) woff += wtot[q & 1][ww];
        float base = woff + (x - t3);  // exclusive prefix for this lane
        aw[0] = pc[0] * (base + t0);
        aw[1] = pc[1] * (base + t1);
        aw[2] = pc[2] * (base + t2);
        aw[3] = pc[3] * (base + t3);
        *(float4*)(A + (size_t)q * 1024) = make_float4(aw[0], aw[1], aw[2], aw[3]);
    }
}

// ---------------------------------------------------------------------------
// Beta -> fp16. One block per (b,q): all hc x hm computed in-block so the 4
// alpha rows load exactly once. LDS swizzle SW(k)=k+(k>>3).
// Grid: (q=128, b=8), 256 threads, 4 k each.
// ---------------------------------------------------------------------------
#define SW(k) ((k) + ((k) >> 3))

__global__ __launch_bounds__(256) void beta_kernel(
    const float* __restrict__ e_chunk, const float* __restrict__ alpha,
    _Float16* __restrict__ beta)
{
    __shared__ float sm[SW(1023) + 1];
    __shared__ float tm[SW(1027) + 1];
    __shared__ float red[4];
    const int q = blockIdx.x, b = blockIdx.y;
    const int tid = threadIdx.x;
    const int lane = tid & 63, wid = tid >> 6;
    const int k4 = tid * 4;

    // alpha rows for all 4 hm (read once per block)
    float av[4][4];
#pragma unroll
    for (int hm = 0; hm < 4; ++hm)
        *(float4*)&av[hm][0] =
            *(const float4*)(alpha + (((size_t)b * 4 + hm) * 128 + q) * 1024 + k4);

    if (tid < 4) tm[SW(1024 + tid)] = 0.f;  // fwd-window zero pad (set once)

    for (int hc = 0; hc < 4; ++hc) {
        float4 ev = *(const float4*)(e_chunk + (((size_t)b * 4 + hc) * 128 + q) * 1024 + k4);
        float e[4] = {ev.x, ev.y, ev.z, ev.w};

        float mx = fmaxf(fmaxf(e[0], e[1]), fmaxf(e[2], e[3]));
#pragma unroll
        for (int off = 32; off >= 1; off >>= 1)
            mx = fmaxf(mx, __shfl_xor(mx, off, 64));
        if (lane == 0) red[wid] = mx;
        __syncthreads();
        mx = fmaxf(fmaxf(red[0], red[1]), fmaxf(red[2], red[3]));

        float sx[4];
#pragma unroll
        for (int i = 0; i < 4; ++i) {
            sx[i] = fmaxf(expf(e[i] - mx), 1e-5f);
            sm[SW(k4 + i)] = sx[i];
        }
        __syncthreads();

        float den[4];
#pragma unroll
        for (int i = 0; i < 4; ++i) {
            int k = k4 + i;
            float d = sm[SW(k)];
            if (k >= 1) d += sm[SW(k - 1)];
            if (k >= 2) d += sm[SW(k - 2)];
            if (k >= 3) d += sm[SW(k - 3)];
            den[i] = d;
        }

#pragma unroll
        for (int hm = 0; hm < 4; ++hm) {
            float t[4] = {av[hm][0] / den[0], av[hm][1] / den[1],
                          av[hm][2] / den[2], av[hm][3] / den[3]};
#pragma unroll
            for (int i = 0; i < 4; ++i) tm[SW(k4 + i)] = t[i];
            __syncthreads();
            float o[4];
#pragma unroll
            for (int i = 0; i < 4; ++i) {
                int k = k4 + i;
                float ms = tm[SW(k)] + tm[SW(k + 1)] + tm[SW(k + 2)] + tm[SW(k + 3)];
                o[i] = sx[i] * ms;
            }
            _Float16* Brow = beta + (((size_t)b * 16 + hm * 4 + hc) * 128 + q) * 1024;
            half4v hv = {(_Float16)o[0], (_Float16)o[1], (_Float16)o[2], (_Float16)o[3]};
            *(half4v*)(Brow + k4) = hv;
            __syncthreads();  // tm reread-safe before next hm overwrite
        }
    }
}

// ---------------------------------------------------------------------------
// Context: cv[b,q,h*32+d] = sum_k beta16[b,h,q,k] * V[b,k,h*32+d]
// ---------------------------------------------------------------------------
__global__ __launch_bounds__(256) void context_kernel(
    const _Float16* __restrict__ beta, const float* __restrict__ V,
    float* __restrict__ cv)
{
    __shared__ float bS[32][64];
    __shared__ float vS[32][32];
    const int qh = blockIdx.x, h = blockIdx.y, b = blockIdx.z;
    const int tid = threadIdx.x;
    const int ty = tid >> 3, tx = tid & 7;
    const int q0 = qh * 64;

    const _Float16* Bbase = beta + (((size_t)b * 16 + h) * 128 + q0) * 1024;
    const float* Vbase = V + (size_t)b * 1024 * 512 + h * 32;

    float acc[2][4];
#pragma unroll
    for (int i = 0; i < 2; ++i)
#pragma unroll
        for (int j = 0; j < 4; ++j) acc[i][j] = 0.f;

    for (int k0 = 0; k0 < 1024; k0 += 32) {
        {
            int r = tid >> 2, c = tid & 3;
            half8 v = *(const half8*)(Bbase + (size_t)r * 1024 + k0 + c * 8);
#pragma unroll
            for (int j = 0; j < 8; ++j) bS[c * 8 + j][r] = (float)v[j];
        }
        {
            int kk = tid >> 3, c = tid & 7;
            float4 v = *(const float4*)(Vbase + (size_t)(k0 + kk) * 512 + c * 4);
            *(float4*)&vS[kk][c * 4] = v;
        }
        __syncthreads();
#pragma unroll
        for (int kk = 0; kk < 32; ++kk) {
            float a0 = bS[kk][ty * 2], a1 = bS[kk][ty * 2 + 1];
            float bb[4];
            *(float4*)bb = *(const float4*)&vS[kk][tx * 4];
#pragma unroll
            for (int j = 0; j < 4; ++j) {
                acc[0][j] = fmaf(a0, bb[j], acc[0][j]);
                acc[1][j] = fmaf(a1, bb[j], acc[1][j]);
            }
        }
        __syncthreads();
    }
#pragma unroll
    for (int i = 0; i < 2; ++i) {
        float* Cp = cv + ((size_t)b * 128 + q0 + ty * 2 + i) * 512 + h * 32 + tx * 4;
        *(float4*)Cp = make_float4(acc[i][0], acc[i][1], acc[i][2], acc[i][3]);
    }
}

// ---------------------------------------------------------------------------
extern "C" void kernel_launch(void* const* d_in, const int* in_sizes, int n_in,
                              void* d_out, int out_size, void* d_ws, size_t ws_size,
                              hipStream_t stream)
{
    const float* key_x   = (const float*)d_in[0];
    const float* query_x = (const float*)d_in[1];
    const int*   mask    = (const int*)d_in[2];
    const float* wk_m = (const float*)d_in[3];
    const float* bk_m = (const float*)d_in[4];
    const float* wq_m = (const float*)d_in[5];
    const float* bq_m = (const float*)d_in[6];
    const float* r    = (const float*)d_in[7];
    const float* wk_c = (const float*)d_in[8];
    const float* bk_c = (const float*)d_in[9];
    const float* wq_c = (const float*)d_in[10];
    const float* bq_c = (const float*)d_in[11];
    const float* wv   = (const float*)d_in[12];
    const float* bv   = (const float*)d_in[13];
    const float* wo   = (const float*)d_in[14];
    const float* bo   = (const float*)d_in[15];
    float* out = (float*)d_out;

    float* ws = (float*)d_ws;
    _Float16* hws = (_Float16*)d_ws;
    const size_t MEGF = 1024 * 1024;
    // Float-unit layout (fp16 offsets are 2x float offsets):
    //  phase A: K16 f[0,2), Q16 f[4,4.25), Wt5 f[4.5,5.25),
    //           Km16 f[6,8), Kc16 f[8,10), Qm16 f[10,10.125),
    //           Qc16 f[10.25,10.375), e_mono f[11,15), e_chunk f[15,19),
    //           V f[19,23)
    //  phase B (alpha): pcp = e_mono in-place; invcp f[0,4) (K16/Q16 dead);
    //           alpha f[23,27)
    //  phase C: beta16 f[0,8) (invcp/Km16/Kc16 dead), cv f[27,27.5)
    //  phase D: Wt_wo f[27.5,27.625), cv16 f[27.75,28). Peak 28 MEGF.
    _Float16* K16   = hws;                          // f 0
    _Float16* Q16   = hws + 8 * MEGF;               // f 4
    _Float16* Wt5   = hws + 9 * MEGF;               // f 4.5
    _Float16* Km16  = hws + 12 * MEGF;              // f 6
    _Float16* Kc16  = hws + 16 * MEGF;              // f 8
    _Float16* Qm16  = hws + 20 * MEGF;              // f 10
    _Float16* Qc16  = hws + 20 * MEGF + MEGF / 2;   // f 10.25
    float* e_mono  = ws + 11 * MEGF;
    float* pcp     = e_mono;                        // in-place
    float* invcp   = ws;                            // f 0 (over dead K16/Q16)
    float* e_chunk = ws + 15 * MEGF;
    float* V       = ws + 19 * MEGF;
    float* alpha   = ws + 23 * MEGF;
    _Float16* beta16 = hws;                         // f 0 (phase C overlay)
    float* cv      = ws + 27 * MEGF;
    _Float16* Wt_wo = hws + 55 * MEGF;              // f 27.5
    _Float16* cv16  = hws + 55 * MEGF + MEGF / 2;   // f 27.75

    // 0) fp16 packing
    cvt_f32_f16<<<dim3(4096), 256, 0, stream>>>(key_x, K16);
    cvt_f32_f16<<<dim3(512), 256, 0, stream>>>(query_x, Q16);
    pack_weights<<<dim3(8, 8, 5), 256, 0, stream>>>(wk_m, wk_c, wv, wq_m, wq_c, Wt5);
    // 1) key-side projections (M=8192): Km16 (f16), Kc16 (f16), V (f32)
    mfma_proj<<<dim3(64, 12), 256, 0, stream>>>(
        K16, Wt5, bk_m, Km16, bk_c, Kc16, bv, V, 0b011);
    // 2) query-side projections (M=1024): Qm16, Qc16 (f16)
    mfma_proj<<<dim3(8, 8), 256, 0, stream>>>(
        Q16, Wt5 + (size_t)3 * 262144, bq_m, Qm16, bq_c, Qc16, bq_c, Qc16, 0b011);
    // 3) energies via MFMA
    energy_mfma<<<dim3(8, 4, 8), 256, 0, stream>>>(Qm16, Km16, mask, e_mono, r, 1);
    energy_mfma<<<dim3(8, 4, 8), 256, 0, stream>>>(Qc16, Kc16, mask, e_chunk, r, 0);
    // 4) monotonic alpha: parallel transcendentals + 4-wave k-split scan
    alpha_pre<<<dim3(1024), 256, 0, stream>>>(e_mono, pcp, invcp);
    alpha_scan<<<dim3(32), 256, 0, stream>>>(pcp, invcp, alpha);
    // 5) chunkwise beta (fp16 out), one block per (b,q)
    beta_kernel<<<dim3(128, 8), 256, 0, stream>>>(e_chunk, alpha, beta16);
    // 6) context vectors
    context_kernel<<<dim3(2, 16, 8), 256, 0, stream>>>(beta16, V, cv);
    // 7) output projection via MFMA (M=1024, fp32 out)
    pack_weights<<<dim3(8, 8, 1), 256, 0, stream>>>(wo, wo, wo, wo, wo, Wt_wo);
    cvt_f32_f16<<<dim3(512), 256, 0, stream>>>(cv, cv16);
    mfma_proj<<<dim3(8, 4), 256, 0, stream>>>(
        cv16, Wt_wo, bo, out, bo, out, bo, out, 0b000);
}

// Round 10
// 329.277 us; speedup vs baseline: 1.2076x; 1.2076x over previous
//
#include <hip/hip_runtime.h>
#include <hip/hip_bf16.h>

// MoChA. Round 10: (1) alpha_scan back to R8 single-wave structure but with
// DPP wave scan (row_shr/row_bcast, ~VALU latency) replacing ds-based
// __shfl_up (~120cyc/hop) — the scan was shuffle-latency bound; (2) merged
// prep kernel (cvt key/query + pack 6 weights) and merged energy launch.
// B=8, Q=128, K=1024, D=512, HM=HC=4, CHUNK=4.

#define NEG_INF (-3.402823466e38f)
#define EPS_MOCHA 1e-6f
#define INV_SCALE 0.04419417382415922f  // 1/sqrt(512)

typedef _Float16 half8 __attribute__((ext_vector_type(8)));
typedef _Float16 half4v __attribute__((ext_vector_type(4)));
typedef float f32x4 __attribute__((ext_vector_type(4)));

// ---------------------------------------------------------------------------
// Wave64 inclusive add-scan via DPP (GCN classic): 6 VALU-latency steps.
// ---------------------------------------------------------------------------
__device__ __forceinline__ float wave_incl_scan(float x)
{
    int v;
    v = __builtin_amdgcn_update_dpp(0, __builtin_bit_cast(int, x), 0x111, 0xF, 0xF, false);
    x += __builtin_bit_cast(float, v);   // row_shr:1
    v = __builtin_amdgcn_update_dpp(0, __builtin_bit_cast(int, x), 0x112, 0xF, 0xF, false);
    x += __builtin_bit_cast(float, v);   // row_shr:2
    v = __builtin_amdgcn_update_dpp(0, __builtin_bit_cast(int, x), 0x114, 0xF, 0xF, false);
    x += __builtin_bit_cast(float, v);   // row_shr:4
    v = __builtin_amdgcn_update_dpp(0, __builtin_bit_cast(int, x), 0x118, 0xF, 0xF, false);
    x += __builtin_bit_cast(float, v);   // row_shr:8 -> row-inclusive
    v = __builtin_amdgcn_update_dpp(0, __builtin_bit_cast(int, x), 0x142, 0xA, 0xF, false);
    x += __builtin_bit_cast(float, v);   // row_bcast:15 -> rows 1,3
    v = __builtin_amdgcn_update_dpp(0, __builtin_bit_cast(int, x), 0x143, 0xC, 0xF, false);
    x += __builtin_bit_cast(float, v);   // row_bcast:31 -> rows 2,3
    return x;
}

// ---------------------------------------------------------------------------
// prep_kernel: one launch for all input packing.
//  blocks [0,4096): key_x -> K16 (fp16)
//  blocks [4096,4608): query_x -> Q16
//  blocks [4608,4992): transpose-pack 6 weights (wk_m,wk_c,wv,wq_m,wq_c,wo)
// ---------------------------------------------------------------------------
__global__ __launch_bounds__(256) void prep_kernel(
    const float* __restrict__ key_x, const float* __restrict__ query_x,
    const float* __restrict__ wk_m, const float* __restrict__ wk_c,
    const float* __restrict__ wv, const float* __restrict__ wq_m,
    const float* __restrict__ wq_c, const float* __restrict__ wo,
    _Float16* __restrict__ K16, _Float16* __restrict__ Q16,
    _Float16* __restrict__ Wt5, _Float16* __restrict__ Wt_wo)
{
    __shared__ float T[64][65];
    const int bid = blockIdx.x;
    const int t = threadIdx.x;
    if (bid < 4608) {
        const float* in = (bid < 4096) ? key_x : query_x;
        _Float16* out = (bid < 4096) ? K16 : Q16;
        const size_t i = (size_t)(bid < 4096 ? bid : bid - 4096) * 256 + t;
        float4 v = *(const float4*)(in + i * 4);
        half4v h = {(_Float16)v.x, (_Float16)v.y, (_Float16)v.z, (_Float16)v.w};
        *(half4v*)(out + i * 4) = h;
        return;
    }
    const int idx = bid - 4608;
    const int z = idx >> 6, tile = idx & 63;
    const float* W = (z == 0) ? wk_m : (z == 1) ? wk_c : (z == 2) ? wv
                   : (z == 3) ? wq_m : (z == 4) ? wq_c : wo;
    _Float16* O = (z < 5) ? (Wt5 + (size_t)z * 262144) : Wt_wo;
    const int n0 = (tile & 7) * 64, k0 = (tile >> 3) * 64;
    const int rr = t >> 4, cc = (t & 15) * 4;
#pragma unroll
    for (int r = 0; r < 4; ++r) {
        int k = r * 16 + rr;
        float4 v = *(const float4*)(W + (size_t)(k0 + k) * 512 + n0 + cc);
        T[k][cc + 0] = v.x; T[k][cc + 1] = v.y;
        T[k][cc + 2] = v.z; T[k][cc + 3] = v.w;
    }
    __syncthreads();
    const int nn = t >> 2, kc = (t & 3) * 16;
    _Float16 tmp[16];
#pragma unroll
    for (int i = 0; i < 16; ++i) tmp[i] = (_Float16)T[kc + i][nn];
    _Float16* Op = O + (size_t)(n0 + nn) * 512 + k0 + kc;
    *(half8*)(Op)     = *(half8*)&tmp[0];
    *(half8*)(Op + 8) = *(half8*)&tmp[8];
}

// ---------------------------------------------------------------------------
// cvt: fp32 -> fp16 (still used for cv -> cv16).
// ---------------------------------------------------------------------------
__global__ __launch_bounds__(256) void cvt_f32_f16(
    const float* __restrict__ in, _Float16* __restrict__ out)
{
    const size_t i = (size_t)blockIdx.x * 256 + threadIdx.x;
    float4 v = *(const float4*)(in + i * 4);
    half4v h = {(_Float16)v.x, (_Float16)v.y, (_Float16)v.z, (_Float16)v.w};
    *(half4v*)(out + i * 4) = h;
}

// ---------------------------------------------------------------------------
// MFMA fragment helpers (16x16x32 f16, fp32 acc); k-contiguous rows stride 512.
// ---------------------------------------------------------------------------
__device__ __forceinline__ void load_frags(
    const _Float16* Ap, const _Float16* Bp, int kk, half8 a[4], half8 b[4])
{
#pragma unroll
    for (int t = 0; t < 4; ++t) {
        a[t] = *(const half8*)(Ap + (size_t)t * 16 * 512 + kk);
        b[t] = *(const half8*)(Bp + (size_t)t * 16 * 512 + kk);
    }
}

__device__ __forceinline__ void mfma_step(half8 a[4], half8 b[4], f32x4 acc[4][4])
{
#pragma unroll
    for (int mt = 0; mt < 4; ++mt)
#pragma unroll
        for (int nt = 0; nt < 4; ++nt)
            acc[mt][nt] = __builtin_amdgcn_mfma_f32_16x16x32_f16(
                a[mt], b[nt], acc[mt][nt], 0, 0, 0);
}

// ---------------------------------------------------------------------------
// MFMA projection GEMM: C[m][n] = sum_k A16[m][k]*Wt[n][k] + bias.
// Block 256 = 2x2 waves, tile 128x128, wave 64x64, K=512, 3-deep pipeline.
// f16_mask bit g: C stored fp16.
// ---------------------------------------------------------------------------
__global__ __launch_bounds__(256) void mfma_proj(
    const _Float16* __restrict__ A16, const _Float16* __restrict__ Wt_base,
    const float* __restrict__ bias0, void* __restrict__ C0,
    const float* __restrict__ bias1, void* __restrict__ C1,
    const float* __restrict__ bias2, void* __restrict__ C2,
    int f16_mask)
{
    const int tid = threadIdx.x;
    const int lane = tid & 63, wave = tid >> 6;
    const int wm = wave >> 1, wn = wave & 1;
    const int col = lane & 15, quad = lane >> 4;
    const int g = blockIdx.y >> 2, nt128 = blockIdx.y & 3;
    const _Float16* Wt = Wt_base + (size_t)g * 262144;
    const float* bias = (g == 0) ? bias0 : (g == 1) ? bias1 : bias2;
    void*        Cv   = (g == 0) ? C0    : (g == 1) ? C1    : C2;
    const int f16o = (f16_mask >> g) & 1;
    const int m0 = blockIdx.x * 128, n0 = nt128 * 128;

    const _Float16* Ap = A16 + (size_t)(m0 + wm * 64 + col) * 512 + quad * 8;
    const _Float16* Bp = Wt  + (size_t)(n0 + wn * 64 + col) * 512 + quad * 8;

    f32x4 acc[4][4];
#pragma unroll
    for (int mt = 0; mt < 4; ++mt)
#pragma unroll
        for (int nt = 0; nt < 4; ++nt) acc[mt][nt] = (f32x4)0.f;

    half8 ab[3][4], bb[3][4];
    load_frags(Ap, Bp, 0, ab[0], bb[0]);
    load_frags(Ap, Bp, 32, ab[1], bb[1]);
#pragma unroll
    for (int ks = 0; ks < 16; ++ks) {
        const int cur = ks % 3, nxt = (ks + 2) % 3;
        if (ks + 2 < 16)
            load_frags(Ap, Bp, (ks + 2) * 32, ab[nxt], bb[nxt]);
        mfma_step(ab[cur], bb[cur], acc);
    }

    float bnt[4];
#pragma unroll
    for (int nt = 0; nt < 4; ++nt)
        bnt[nt] = bias[n0 + wn * 64 + nt * 16 + col];
#pragma unroll
    for (int mt = 0; mt < 4; ++mt) {
        const int rowb = m0 + wm * 64 + mt * 16 + quad * 4;
#pragma unroll
        for (int nt = 0; nt < 4; ++nt) {
            const int cc = n0 + wn * 64 + nt * 16 + col;
#pragma unroll
            for (int r = 0; r < 4; ++r) {
                float v = acc[mt][nt][r] + bnt[nt];
                if (f16o)
                    ((_Float16*)Cv)[(size_t)(rowb + r) * 512 + cc] = (_Float16)v;
                else
                    ((float*)Cv)[(size_t)(rowb + r) * 512 + cc] = v;
            }
        }
    }
}

// ---------------------------------------------------------------------------
// Energy via MFMA, both heads in one launch. Grid: (kt=8, h=4, z=16);
// z<8: mono head (b=z, +r, -> e_mono); z>=8: chunk head (b=z-8, -> e_chunk).
// ---------------------------------------------------------------------------
__global__ __launch_bounds__(256) void energy_mfma(
    const _Float16* __restrict__ Qm, const _Float16* __restrict__ Km,
    const _Float16* __restrict__ Qc, const _Float16* __restrict__ Kc,
    const int* __restrict__ mask, float* __restrict__ e_mono,
    float* __restrict__ e_chunk, const float* __restrict__ r_ptr)
{
    const int tid = threadIdx.x;
    const int lane = tid & 63, wave = tid >> 6;
    const int wm = wave >> 1, wn = wave & 1;
    const int col = lane & 15, quad = lane >> 4;
    const int kt0 = blockIdx.x * 128;
    const int h = blockIdx.y;
    const int z = blockIdx.z;
    const int b = z & 7;
    const bool mono = z < 8;
    const _Float16* Qp = mono ? Qm : Qc;
    const _Float16* Kp = mono ? Km : Kc;
    float* out = mono ? e_mono : e_chunk;
    const float rv = mono ? r_ptr[0] : 0.f;

    const _Float16* Ap = Qp + (size_t)(b * 128 + wm * 64 + col) * 512 + h * 128 + quad * 8;
    const _Float16* Bp = Kp + (size_t)(b * 1024 + kt0 + wn * 64 + col) * 512 + h * 128 + quad * 8;

    f32x4 acc[4][4];
#pragma unroll
    for (int mt = 0; mt < 4; ++mt)
#pragma unroll
        for (int nt = 0; nt < 4; ++nt) acc[mt][nt] = (f32x4)0.f;

    half8 ab[3][4], bb[3][4];
    load_frags(Ap, Bp, 0, ab[0], bb[0]);
    load_frags(Ap, Bp, 32, ab[1], bb[1]);
#pragma unroll
    for (int ks = 0; ks < 4; ++ks) {
        const int cur = ks % 3, nxt = (ks + 2) % 3;
        if (ks + 2 < 4)
            load_frags(Ap, Bp, (ks + 2) * 32, ab[nxt], bb[nxt]);
        mfma_step(ab[cur], bb[cur], acc);
    }

#pragma unroll
    for (int mt = 0; mt < 4; ++mt) {
        const int qb = wm * 64 + mt * 16 + quad * 4;
#pragma unroll
        for (int nt = 0; nt < 4; ++nt) {
            const int kc = kt0 + wn * 64 + nt * 16 + col;
#pragma unroll
            for (int r = 0; r < 4; ++r) {
                const int q = qb + r;
                float v = acc[mt][nt][r] * INV_SCALE + rv;
                int mv = mask[((size_t)b * 128 + q) * 1024 + kc];
                out[(((size_t)b * 4 + h) * 128 + q) * 1024 + kc] = mv ? v : NEG_INF;
            }
        }
    }
}

// ---------------------------------------------------------------------------
// alpha_pre: parallel part of the monotonic recurrence (one wave per row,
// 4096 rows). p=sigmoid(e); cp=exp(excl_cumsum(log(max(1-p,eps))));
// pcp=p*cp (in-place over e_mono); invcp=1/max(cp,eps).
// ---------------------------------------------------------------------------
__global__ __launch_bounds__(256) void alpha_pre(
    const float* __restrict__ e_mono, float* __restrict__ pcp,
    float* __restrict__ invcp)
{
    const int tid = threadIdx.x;
    const int lane = tid & 63;
    const int row = blockIdx.x * 4 + (tid >> 6);
    const float* E = e_mono + (size_t)row * 1024 + lane * 16;

    float e[16];
    *(float4*)&e[0]  = *(const float4*)(E);
    *(float4*)&e[4]  = *(const float4*)(E + 4);
    *(float4*)&e[8]  = *(const float4*)(E + 8);
    *(float4*)&e[12] = *(const float4*)(E + 12);

    float p[16], l[16];
#pragma unroll
    for (int i = 0; i < 16; ++i) {
        p[i] = 1.f / (1.f + expf(-e[i]));
        l[i] = logf(fmaxf(1.f - p[i], EPS_MOCHA));
    }
    float incl[16];
    incl[0] = l[0];
#pragma unroll
    for (int i = 1; i < 16; ++i) incl[i] = incl[i - 1] + l[i];
    float total = incl[15];
    float x = wave_incl_scan(total);
    float base = x - total;  // exclusive across lanes

    float o1[16], o2[16];
#pragma unroll
    for (int i = 0; i < 16; ++i) {
        float cl = base + (i ? incl[i - 1] : 0.f);
        float cp = expf(cl);
        o1[i] = p[i] * cp;
        o2[i] = 1.f / fmaxf(cp, EPS_MOCHA);
    }
    float* P = pcp + (size_t)row * 1024 + lane * 16;
    float* I = invcp + (size_t)row * 1024 + lane * 16;
    *(float4*)(P)      = *(float4*)&o1[0];
    *(float4*)(P + 4)  = *(float4*)&o1[4];
    *(float4*)(P + 8)  = *(float4*)&o1[8];
    *(float4*)(P + 12) = *(float4*)&o1[12];
    *(float4*)(I)      = *(float4*)&o2[0];
    *(float4*)(I + 4)  = *(float4*)&o2[4];
    *(float4*)(I + 8)  = *(float4*)&o2[8];
    *(float4*)(I + 12) = *(float4*)&o2[12];
}

// ---------------------------------------------------------------------------
// alpha_scan: one wave per (b,h), 16 k/lane, zero barriers, 4-deep prefetch,
// DPP wave scan on the serial chain.
// Per q: aw = pcp * inclusive_cumsum_k(aw_prev * invcp).
// ---------------------------------------------------------------------------
__global__ __launch_bounds__(64) void alpha_scan(
    const float* __restrict__ pcp, const float* __restrict__ invcp,
    float* __restrict__ alpha)
{
    const int lane = threadIdx.x;
    const int bh = blockIdx.x;
    const float* P = pcp + (size_t)bh * 131072 + lane * 16;
    const float* I = invcp + (size_t)bh * 131072 + lane * 16;
    float* A = alpha + (size_t)bh * 131072 + lane * 16;

    float bp[4][16], bi[4][16];
#pragma unroll
    for (int s = 0; s < 4; ++s) {
        const float* Pq = P + (size_t)s * 1024;
        const float* Iq = I + (size_t)s * 1024;
        *(float4*)&bp[s][0]  = *(const float4*)(Pq);
        *(float4*)&bp[s][4]  = *(const float4*)(Pq + 4);
        *(float4*)&bp[s][8]  = *(const float4*)(Pq + 8);
        *(float4*)&bp[s][12] = *(const float4*)(Pq + 12);
        *(float4*)&bi[s][0]  = *(const float4*)(Iq);
        *(float4*)&bi[s][4]  = *(const float4*)(Iq + 4);
        *(float4*)&bi[s][8]  = *(const float4*)(Iq + 8);
        *(float4*)&bi[s][12] = *(const float4*)(Iq + 12);
    }

    float aw[16];
#pragma unroll
    for (int i = 0; i < 16; ++i) aw[i] = 0.f;
    if (lane == 0) aw[0] = 1.f;

    for (int q4 = 0; q4 < 128; q4 += 4) {
#pragma unroll
        for (int s = 0; s < 4; ++s) {
            const int q = q4 + s;
            float pc[16], ic[16];
#pragma unroll
            for (int i = 0; i < 16; ++i) { pc[i] = bp[s][i]; ic[i] = bi[s][i]; }
            if (q + 4 < 128) {  // refill slot s for q+4 (issues before chain)
                const float* Pq = P + (size_t)(q + 4) * 1024;
                const float* Iq = I + (size_t)(q + 4) * 1024;
                *(float4*)&bp[s][0]  = *(const float4*)(Pq);
                *(float4*)&bp[s][4]  = *(const float4*)(Pq + 4);
                *(float4*)&bp[s][8]  = *(const float4*)(Pq + 8);
                *(float4*)&bp[s][12] = *(const float4*)(Pq + 12);
                *(float4*)&bi[s][0]  = *(const float4*)(Iq);
                *(float4*)&bi[s][4]  = *(const float4*)(Iq + 4);
                *(float4*)&bi[s][8]  = *(const float4*)(Iq + 8);
                *(float4*)&bi[s][12] = *(const float4*)(Iq + 12);
            }

            float incl[16];
            incl[0] = aw[0] * ic[0];
#pragma unroll
            for (int i = 1; i < 16; ++i) incl[i] = incl[i - 1] + aw[i] * ic[i];
            float total = incl[15];
            float x = wave_incl_scan(total);
            float base = x - total;  // exclusive across lanes
#pragma unroll
            for (int i = 0; i < 16; ++i) aw[i] = pc[i] * (base + incl[i]);

            float* Aq = A + (size_t)q * 1024;
            *(float4*)(Aq)      = *(float4*)&aw[0];
            *(float4*)(Aq + 4)  = *(float4*)&aw[4];
            *(float4*)(Aq + 8)  = *(float4*)&aw[8];
            *(float4*)(Aq + 12) = *(float4*)&aw[12];
        }
    }
}

// ---------------------------------------------------------------------------
// Beta -> fp16. One block per (b,q): all hc x hm in-block (alpha read once).
// LDS swizzle SW(k)=k+(k>>3). Grid: (q=128, b=8), 256 threads, 4 k each.
// ---------------------------------------------------------------------------
#define SW(k) ((k) + ((k) >> 3))

__global__ __launch_bounds__(256) void beta_kernel(
    const float* __restrict__ e_chunk, const float* __restrict__ alpha,
    _Float16* __restrict__ beta)
{
    __shared__ float sm[SW(1023) + 1];
    __shared__ float tm[SW(1027) + 1];
    __shared__ float red[4];
    const int q = blockIdx.x, b = blockIdx.y;
    const int tid = threadIdx.x;
    const int lane = tid & 63, wid = tid >> 6;
    const int k4 = tid * 4;

    float av[4][4];
#pragma unroll
    for (int hm = 0; hm < 4; ++hm)
        *(float4*)&av[hm][0] =
            *(const float4*)(alpha + (((size_t)b * 4 + hm) * 128 + q) * 1024 + k4);

    if (tid < 4) tm[SW(1024 + tid)] = 0.f;  // fwd-window zero pad (set once)

    for (int hc = 0; hc < 4; ++hc) {
        float4 ev = *(const float4*)(e_chunk + (((size_t)b * 4 + hc) * 128 + q) * 1024 + k4);
        float e[4] = {ev.x, ev.y, ev.z, ev.w};

        float mx = fmaxf(fmaxf(e[0], e[1]), fmaxf(e[2], e[3]));
#pragma unroll
        for (int off = 32; off >= 1; off >>= 1)
            mx = fmaxf(mx, __shfl_xor(mx, off, 64));
        if (lane == 0) red[wid] = mx;
        __syncthreads();
        mx = fmaxf(fmaxf(red[0], red[1]), fmaxf(red[2], red[3]));

        float sx[4];
#pragma unroll
        for (int i = 0; i < 4; ++i) {
            sx[i] = fmaxf(expf(e[i] - mx), 1e-5f);
            sm[SW(k4 + i)] = sx[i];
        }
        __syncthreads();

        float den[4];
#pragma unroll
        for (int i = 0; i < 4; ++i) {
            int k = k4 + i;
            float d = sm[SW(k)];
            if (k >= 1) d += sm[SW(k - 1)];
            if (k >= 2) d += sm[SW(k - 2)];
            if (k >= 3) d += sm[SW(k - 3)];
            den[i] = d;
        }

#pragma unroll
        for (int hm = 0; hm < 4; ++hm) {
            float t[4] = {av[hm][0] / den[0], av[hm][1] / den[1],
                          av[hm][2] / den[2], av[hm][3] / den[3]};
#pragma unroll
            for (int i = 0; i < 4; ++i) tm[SW(k4 + i)] = t[i];
            __syncthreads();
            float o[4];
#pragma unroll
            for (int i = 0; i < 4; ++i) {
                int k = k4 + i;
                float ms = tm[SW(k)] + tm[SW(k + 1)] + tm[SW(k + 2)] + tm[SW(k + 3)];
                o[i] = sx[i] * ms;
            }
            _Float16* Brow = beta + (((size_t)b * 16 + hm * 4 + hc) * 128 + q) * 1024;
            half4v hv = {(_Float16)o[0], (_Float16)o[1], (_Float16)o[2], (_Float16)o[3]};
            *(half4v*)(Brow + k4) = hv;
            __syncthreads();
        }
    }
}

// ---------------------------------------------------------------------------
// Context: cv[b,q,h*32+d] = sum_k beta16[b,h,q,k] * V[b,k,h*32+d]
// ---------------------------------------------------------------------------
__global__ __launch_bounds__(256) void context_kernel(
    const _Float16* __restrict__ beta, const float* __restrict__ V,
    float* __restrict__ cv)
{
    __shared__ float bS[32][64];
    __shared__ float vS[32][32];
    const int qh = blockIdx.x, h = blockIdx.y, b = blockIdx.z;
    const int tid = threadIdx.x;
    const int ty = tid >> 3, tx = tid & 7;
    const int q0 = qh * 64;

    const _Float16* Bbase = beta + (((size_t)b * 16 + h) * 128 + q0) * 1024;
    const float* Vbase = V + (size_t)b * 1024 * 512 + h * 32;

    float acc[2][4];
#pragma unroll
    for (int i = 0; i < 2; ++i)
#pragma unroll
        for (int j = 0; j < 4; ++j) acc[i][j] = 0.f;

    for (int k0 = 0; k0 < 1024; k0 += 32) {
        {
            int r = tid >> 2, c = tid & 3;
            half8 v = *(const half8*)(Bbase + (size_t)r * 1024 + k0 + c * 8);
#pragma unroll
            for (int j = 0; j < 8; ++j) bS[c * 8 + j][r] = (float)v[j];
        }
        {
            int kk = tid >> 3, c = tid & 7;
            float4 v = *(const float4*)(Vbase + (size_t)(k0 + kk) * 512 + c * 4);
            *(float4*)&vS[kk][c * 4] = v;
        }
        __syncthreads();
#pragma unroll
        for (int kk = 0; kk < 32; ++kk) {
            float a0 = bS[kk][ty * 2], a1 = bS[kk][ty * 2 + 1];
            float bb[4];
            *(float4*)bb = *(const float4*)&vS[kk][tx * 4];
#pragma unroll
            for (int j = 0; j < 4; ++j) {
                acc[0][j] = fmaf(a0, bb[j], acc[0][j]);
                acc[1][j] = fmaf(a1, bb[j], acc[1][j]);
            }
        }
        __syncthreads();
    }
#pragma unroll
    for (int i = 0; i < 2; ++i) {
        float* Cp = cv + ((size_t)b * 128 + q0 + ty * 2 + i) * 512 + h * 32 + tx * 4;
        *(float4*)Cp = make_float4(acc[i][0], acc[i][1], acc[i][2], acc[i][3]);
    }
}

// ---------------------------------------------------------------------------
extern "C" void kernel_launch(void* const* d_in, const int* in_sizes, int n_in,
                              void* d_out, int out_size, void* d_ws, size_t ws_size,
                              hipStream_t stream)
{
    const float* key_x   = (const float*)d_in[0];
    const float* query_x = (const float*)d_in[1];
    const int*   mask    = (const int*)d_in[2];
    const float* wk_m = (const float*)d_in[3];
    const float* bk_m = (const float*)d_in[4];
    const float* wq_m = (const float*)d_in[5];
    const float* bq_m = (const float*)d_in[6];
    const float* r    = (const float*)d_in[7];
    const float* wk_c = (const float*)d_in[8];
    const float* bk_c = (const float*)d_in[9];
    const float* wq_c = (const float*)d_in[10];
    const float* bq_c = (const float*)d_in[11];
    const float* wv   = (const float*)d_in[12];
    const float* bv   = (const float*)d_in[13];
    const float* wo   = (const float*)d_in[14];
    const float* bo   = (const float*)d_in[15];
    float* out = (float*)d_out;

    float* ws = (float*)d_ws;
    _Float16* hws = (_Float16*)d_ws;
    const size_t MEGF = 1024 * 1024;
    // Float-unit layout (fp16 offsets are 2x float offsets):
    //  phase A: K16 f[0,2), Q16 f[4,4.25), Wt5 f[4.5,5.25),
    //           Km16 f[6,8), Kc16 f[8,10), Qm16 f[10,10.125),
    //           Qc16 f[10.25,10.375), e_mono f[11,15), e_chunk f[15,19),
    //           V f[19,23), Wt_wo f[27.5,27.625)
    //  phase B (alpha): pcp = e_mono in-place; invcp f[0,4) (K16/Q16 dead);
    //           alpha f[23,27)
    //  phase C: beta16 f[0,8) (invcp/Km16/Kc16 dead), cv f[27,27.5)
    //  phase D: cv16 f[27.75,28). Peak 28 MEGF.
    _Float16* K16   = hws;                          // f 0
    _Float16* Q16   = hws + 8 * MEGF;               // f 4
    _Float16* Wt5   = hws + 9 * MEGF;               // f 4.5
    _Float16* Km16  = hws + 12 * MEGF;              // f 6
    _Float16* Kc16  = hws + 16 * MEGF;              // f 8
    _Float16* Qm16  = hws + 20 * MEGF;              // f 10
    _Float16* Qc16  = hws + 20 * MEGF + MEGF / 2;   // f 10.25
    float* e_mono  = ws + 11 * MEGF;
    float* pcp     = e_mono;                        // in-place
    float* invcp   = ws;                            // f 0 (over dead K16/Q16)
    float* e_chunk = ws + 15 * MEGF;
    float* V       = ws + 19 * MEGF;
    float* alpha   = ws + 23 * MEGF;
    _Float16* beta16 = hws;                         // f 0 (phase C overlay)
    float* cv      = ws + 27 * MEGF;
    _Float16* Wt_wo = hws + 55 * MEGF;              // f 27.5
    _Float16* cv16  = hws + 55 * MEGF + MEGF / 2;   // f 27.75

    // 0) merged prep: cvt key/query + pack 6 weights
    prep_kernel<<<dim3(4992), 256, 0, stream>>>(
        key_x, query_x, wk_m, wk_c, wv, wq_m, wq_c, wo,
        K16, Q16, Wt5, Wt_wo);
    // 1) key-side projections (M=8192): Km16 (f16), Kc16 (f16), V (f32)
    mfma_proj<<<dim3(64, 12), 256, 0, stream>>>(
        K16, Wt5, bk_m, Km16, bk_c, Kc16, bv, V, 0b011);
    // 2) query-side projections (M=1024): Qm16, Qc16 (f16)
    mfma_proj<<<dim3(8, 8), 256, 0, stream>>>(
        Q16, Wt5 + (size_t)3 * 262144, bq_m, Qm16, bq_c, Qc16, bq_c, Qc16, 0b011);
    // 3) both energies in one launch
    energy_mfma<<<dim3(8, 4, 16), 256, 0, stream>>>(
        Qm16, Km16, Qc16, Kc16, mask, e_mono, e_chunk, r);
    // 4) monotonic alpha: parallel transcendentals + DPP-scan recurrence
    alpha_pre<<<dim3(1024), 256, 0, stream>>>(e_mono, pcp, invcp);
    alpha_scan<<<dim3(32), 64, 0, stream>>>(pcp, invcp, alpha);
    // 5) chunkwise beta (fp16 out), one block per (b,q)
    beta_kernel<<<dim3(128, 8), 256, 0, stream>>>(e_chunk, alpha, beta16);
    // 6) context vectors
    context_kernel<<<dim3(2, 16, 8), 256, 0, stream>>>(beta16, V, cv);
    // 7) output projection via MFMA (M=1024, fp32 out)
    cvt_f32_f16<<<dim3(512), 256, 0, stream>>>(cv, cv16);
    mfma_proj<<<dim3(8, 4), 256, 0, stream>>>(
        cv16, Wt_wo, bo, out, bo, out, bo, out, 0b000);
}

// Round 11
// 292.164 us; speedup vs baseline: 1.3610x; 1.1270x over previous
//
#include <hip/hip_runtime.h>
#include <hip/hip_bf16.h>

// MoChA. Round 11: mfma_proj rewritten as LDS-staged GEMM (m97 shape):
// 128x128 tile, BK=32, padded LDS (stride 40 halfs, 16B-aligned b128),
// global->VGPR prefetch of next tile overlapping MFMA, ds_read_b128 frags.
// Direct-global fragment loads (R6-R10) were latency-bound at 8% MfmaUtil.
// Everything else unchanged from R10 (DPP alpha scan, fused prep, fp16 beta).
// B=8, Q=128, K=1024, D=512, HM=HC=4, CHUNK=4.

#define NEG_INF (-3.402823466e38f)
#define EPS_MOCHA 1e-6f
#define INV_SCALE 0.04419417382415922f  // 1/sqrt(512)

typedef _Float16 half8 __attribute__((ext_vector_type(8)));
typedef _Float16 half4v __attribute__((ext_vector_type(4)));
typedef float f32x4 __attribute__((ext_vector_type(4)));

#define ASTR 40  // LDS row stride in halfs (32 data + 8 pad; 80B, 16B-aligned)

// ---------------------------------------------------------------------------
// Wave64 inclusive add-scan via DPP (GCN classic): 6 VALU-latency steps.
// ---------------------------------------------------------------------------
__device__ __forceinline__ float wave_incl_scan(float x)
{
    int v;
    v = __builtin_amdgcn_update_dpp(0, __builtin_bit_cast(int, x), 0x111, 0xF, 0xF, false);
    x += __builtin_bit_cast(float, v);   // row_shr:1
    v = __builtin_amdgcn_update_dpp(0, __builtin_bit_cast(int, x), 0x112, 0xF, 0xF, false);
    x += __builtin_bit_cast(float, v);   // row_shr:2
    v = __builtin_amdgcn_update_dpp(0, __builtin_bit_cast(int, x), 0x114, 0xF, 0xF, false);
    x += __builtin_bit_cast(float, v);   // row_shr:4
    v = __builtin_amdgcn_update_dpp(0, __builtin_bit_cast(int, x), 0x118, 0xF, 0xF, false);
    x += __builtin_bit_cast(float, v);   // row_shr:8 -> row-inclusive
    v = __builtin_amdgcn_update_dpp(0, __builtin_bit_cast(int, x), 0x142, 0xA, 0xF, false);
    x += __builtin_bit_cast(float, v);   // row_bcast:15 -> rows 1,3
    v = __builtin_amdgcn_update_dpp(0, __builtin_bit_cast(int, x), 0x143, 0xC, 0xF, false);
    x += __builtin_bit_cast(float, v);   // row_bcast:31 -> rows 2,3
    return x;
}

// ---------------------------------------------------------------------------
// prep_kernel: one launch for all input packing.
//  blocks [0,4096): key_x -> K16 (fp16)
//  blocks [4096,4608): query_x -> Q16
//  blocks [4608,4992): transpose-pack 6 weights (wk_m,wk_c,wv,wq_m,wq_c,wo)
// ---------------------------------------------------------------------------
__global__ __launch_bounds__(256) void prep_kernel(
    const float* __restrict__ key_x, const float* __restrict__ query_x,
    const float* __restrict__ wk_m, const float* __restrict__ wk_c,
    const float* __restrict__ wv, const float* __restrict__ wq_m,
    const float* __restrict__ wq_c, const float* __restrict__ wo,
    _Float16* __restrict__ K16, _Float16* __restrict__ Q16,
    _Float16* __restrict__ Wt5, _Float16* __restrict__ Wt_wo)
{
    __shared__ float T[64][65];
    const int bid = blockIdx.x;
    const int t = threadIdx.x;
    if (bid < 4608) {
        const float* in = (bid < 4096) ? key_x : query_x;
        _Float16* out = (bid < 4096) ? K16 : Q16;
        const size_t i = (size_t)(bid < 4096 ? bid : bid - 4096) * 256 + t;
        float4 v = *(const float4*)(in + i * 4);
        half4v h = {(_Float16)v.x, (_Float16)v.y, (_Float16)v.z, (_Float16)v.w};
        *(half4v*)(out + i * 4) = h;
        return;
    }
    const int idx = bid - 4608;
    const int z = idx >> 6, tile = idx & 63;
    const float* W = (z == 0) ? wk_m : (z == 1) ? wk_c : (z == 2) ? wv
                   : (z == 3) ? wq_m : (z == 4) ? wq_c : wo;
    _Float16* O = (z < 5) ? (Wt5 + (size_t)z * 262144) : Wt_wo;
    const int n0 = (tile & 7) * 64, k0 = (tile >> 3) * 64;
    const int rr = t >> 4, cc = (t & 15) * 4;
#pragma unroll
    for (int r = 0; r < 4; ++r) {
        int k = r * 16 + rr;
        float4 v = *(const float4*)(W + (size_t)(k0 + k) * 512 + n0 + cc);
        T[k][cc + 0] = v.x; T[k][cc + 1] = v.y;
        T[k][cc + 2] = v.z; T[k][cc + 3] = v.w;
    }
    __syncthreads();
    const int nn = t >> 2, kc = (t & 3) * 16;
    _Float16 tmp[16];
#pragma unroll
    for (int i = 0; i < 16; ++i) tmp[i] = (_Float16)T[kc + i][nn];
    _Float16* Op = O + (size_t)(n0 + nn) * 512 + k0 + kc;
    *(half8*)(Op)     = *(half8*)&tmp[0];
    *(half8*)(Op + 8) = *(half8*)&tmp[8];
}

// ---------------------------------------------------------------------------
// cvt: fp32 -> fp16 (cv -> cv16).
// ---------------------------------------------------------------------------
__global__ __launch_bounds__(256) void cvt_f32_f16(
    const float* __restrict__ in, _Float16* __restrict__ out)
{
    const size_t i = (size_t)blockIdx.x * 256 + threadIdx.x;
    float4 v = *(const float4*)(in + i * 4);
    half4v h = {(_Float16)v.x, (_Float16)v.y, (_Float16)v.z, (_Float16)v.w};
    *(half4v*)(out + i * 4) = h;
}

__device__ __forceinline__ void mfma_step(half8 a[4], half8 b[4], f32x4 acc[4][4])
{
#pragma unroll
    for (int mt = 0; mt < 4; ++mt)
#pragma unroll
        for (int nt = 0; nt < 4; ++nt)
            acc[mt][nt] = __builtin_amdgcn_mfma_f32_16x16x32_f16(
                a[mt], b[nt], acc[mt][nt], 0, 0, 0);
}

// ---------------------------------------------------------------------------
// MFMA projection GEMM (LDS-staged): C[m][n] = sum_k A16[m][k]*Wt[n][k]+bias.
// Block 256 = 2x2 waves, tile 128x128, wave 64x64 (4x4 frags), BK=32.
// Per step: [barrier] ds_write staged tile [barrier] prefetch next tile
// (global->VGPR, overlaps MFMA) + 8 ds_read_b128 + 16 MFMA.
// f16_mask bit g: C stored fp16. Grid: (M/128, ngroups*4).
// ---------------------------------------------------------------------------
__global__ __launch_bounds__(256) void mfma_proj(
    const _Float16* __restrict__ A16, const _Float16* __restrict__ Wt_base,
    const float* __restrict__ bias0, void* __restrict__ C0,
    const float* __restrict__ bias1, void* __restrict__ C1,
    const float* __restrict__ bias2, void* __restrict__ C2,
    int f16_mask)
{
    __shared__ _Float16 As[128 * ASTR];
    __shared__ _Float16 Bs[128 * ASTR];
    const int tid = threadIdx.x;
    const int lane = tid & 63, wave = tid >> 6;
    const int wm = wave >> 1, wn = wave & 1;
    const int col = lane & 15, quad = lane >> 4;
    const int g = blockIdx.y >> 2, nt128 = blockIdx.y & 3;
    const _Float16* Wt = Wt_base + (size_t)g * 262144;
    const float* bias = (g == 0) ? bias0 : (g == 1) ? bias1 : bias2;
    void*        Cv   = (g == 0) ? C0    : (g == 1) ? C1    : C2;
    const int f16o = (f16_mask >> g) & 1;
    const int m0 = blockIdx.x * 128, n0 = nt128 * 128;

    // staging assignment: thread t -> row = t>>1 (0..127), seg = t&1 (16 halfs)
    const int srow = tid >> 1, sseg = tid & 1;
    const _Float16* Ag = A16 + (size_t)(m0 + srow) * 512 + sseg * 16;
    const _Float16* Bg = Wt  + (size_t)(n0 + srow) * 512 + sseg * 16;
    _Float16* Al = As + srow * ASTR + sseg * 16;
    _Float16* Bl = Bs + srow * ASTR + sseg * 16;

    f32x4 acc[4][4];
#pragma unroll
    for (int mt = 0; mt < 4; ++mt)
#pragma unroll
        for (int nt = 0; nt < 4; ++nt) acc[mt][nt] = (f32x4)0.f;

    const _Float16* Afr = As + (size_t)(wm * 64 + col) * ASTR + quad * 8;
    const _Float16* Bfr = Bs + (size_t)(wn * 64 + col) * ASTR + quad * 8;

    half8 pa0, pa1, pb0, pb1;
    pa0 = *(const half8*)(Ag);
    pa1 = *(const half8*)(Ag + 8);
    pb0 = *(const half8*)(Bg);
    pb1 = *(const half8*)(Bg + 8);

    for (int ks = 0; ks < 16; ++ks) {
        __syncthreads();  // previous step's ds_reads done before overwrite
        *(half8*)(Al)     = pa0;
        *(half8*)(Al + 8) = pa1;
        *(half8*)(Bl)     = pb0;
        *(half8*)(Bl + 8) = pb1;
        __syncthreads();
        if (ks + 1 < 16) {  // prefetch next tile; overlaps MFMA below
            const int k0 = (ks + 1) * 32;
            pa0 = *(const half8*)(Ag + k0);
            pa1 = *(const half8*)(Ag + k0 + 8);
            pb0 = *(const half8*)(Bg + k0);
            pb1 = *(const half8*)(Bg + k0 + 8);
        }
        half8 a[4], b[4];
#pragma unroll
        for (int t = 0; t < 4; ++t) {
            a[t] = *(const half8*)(Afr + (size_t)t * 16 * ASTR);
            b[t] = *(const half8*)(Bfr + (size_t)t * 16 * ASTR);
        }
        mfma_step(a, b, acc);
    }

    float bnt[4];
#pragma unroll
    for (int nt = 0; nt < 4; ++nt)
        bnt[nt] = bias[n0 + wn * 64 + nt * 16 + col];
#pragma unroll
    for (int mt = 0; mt < 4; ++mt) {
        const int rowb = m0 + wm * 64 + mt * 16 + quad * 4;
#pragma unroll
        for (int nt = 0; nt < 4; ++nt) {
            const int cc = n0 + wn * 64 + nt * 16 + col;
#pragma unroll
            for (int r = 0; r < 4; ++r) {
                float v = acc[mt][nt][r] + bnt[nt];
                if (f16o)
                    ((_Float16*)Cv)[(size_t)(rowb + r) * 512 + cc] = (_Float16)v;
                else
                    ((float*)Cv)[(size_t)(rowb + r) * 512 + cc] = v;
            }
        }
    }
}

// ---------------------------------------------------------------------------
// Energy via MFMA, both heads in one launch (direct-global frags, K=128).
// Grid: (kt=8, h=4, z=16); z<8: mono (b=z, +r, e_mono); z>=8: chunk.
// ---------------------------------------------------------------------------
__device__ __forceinline__ void load_frags_g(
    const _Float16* Ap, const _Float16* Bp, int kk, half8 a[4], half8 b[4])
{
#pragma unroll
    for (int t = 0; t < 4; ++t) {
        a[t] = *(const half8*)(Ap + (size_t)t * 16 * 512 + kk);
        b[t] = *(const half8*)(Bp + (size_t)t * 16 * 512 + kk);
    }
}

__global__ __launch_bounds__(256) void energy_mfma(
    const _Float16* __restrict__ Qm, const _Float16* __restrict__ Km,
    const _Float16* __restrict__ Qc, const _Float16* __restrict__ Kc,
    const int* __restrict__ mask, float* __restrict__ e_mono,
    float* __restrict__ e_chunk, const float* __restrict__ r_ptr)
{
    const int tid = threadIdx.x;
    const int lane = tid & 63, wave = tid >> 6;
    const int wm = wave >> 1, wn = wave & 1;
    const int col = lane & 15, quad = lane >> 4;
    const int kt0 = blockIdx.x * 128;
    const int h = blockIdx.y;
    const int z = blockIdx.z;
    const int b = z & 7;
    const bool mono = z < 8;
    const _Float16* Qp = mono ? Qm : Qc;
    const _Float16* Kp = mono ? Km : Kc;
    float* out = mono ? e_mono : e_chunk;
    const float rv = mono ? r_ptr[0] : 0.f;

    const _Float16* Ap = Qp + (size_t)(b * 128 + wm * 64 + col) * 512 + h * 128 + quad * 8;
    const _Float16* Bp = Kp + (size_t)(b * 1024 + kt0 + wn * 64 + col) * 512 + h * 128 + quad * 8;

    f32x4 acc[4][4];
#pragma unroll
    for (int mt = 0; mt < 4; ++mt)
#pragma unroll
        for (int nt = 0; nt < 4; ++nt) acc[mt][nt] = (f32x4)0.f;

    half8 ab[3][4], bb[3][4];
    load_frags_g(Ap, Bp, 0, ab[0], bb[0]);
    load_frags_g(Ap, Bp, 32, ab[1], bb[1]);
#pragma unroll
    for (int ks = 0; ks < 4; ++ks) {
        const int cur = ks % 3, nxt = (ks + 2) % 3;
        if (ks + 2 < 4)
            load_frags_g(Ap, Bp, (ks + 2) * 32, ab[nxt], bb[nxt]);
        mfma_step(ab[cur], bb[cur], acc);
    }

#pragma unroll
    for (int mt = 0; mt < 4; ++mt) {
        const int qb = wm * 64 + mt * 16 + quad * 4;
#pragma unroll
        for (int nt = 0; nt < 4; ++nt) {
            const int kc = kt0 + wn * 64 + nt * 16 + col;
#pragma unroll
            for (int r = 0; r < 4; ++r) {
                const int q = qb + r;
                float v = acc[mt][nt][r] * INV_SCALE + rv;
                int mv = mask[((size_t)b * 128 + q) * 1024 + kc];
                out[(((size_t)b * 4 + h) * 128 + q) * 1024 + kc] = mv ? v : NEG_INF;
            }
        }
    }
}

// ---------------------------------------------------------------------------
// alpha_pre: parallel part of the monotonic recurrence (one wave per row).
// ---------------------------------------------------------------------------
__global__ __launch_bounds__(256) void alpha_pre(
    const float* __restrict__ e_mono, float* __restrict__ pcp,
    float* __restrict__ invcp)
{
    const int tid = threadIdx.x;
    const int lane = tid & 63;
    const int row = blockIdx.x * 4 + (tid >> 6);
    const float* E = e_mono + (size_t)row * 1024 + lane * 16;

    float e[16];
    *(float4*)&e[0]  = *(const float4*)(E);
    *(float4*)&e[4]  = *(const float4*)(E + 4);
    *(float4*)&e[8]  = *(const float4*)(E + 8);
    *(float4*)&e[12] = *(const float4*)(E + 12);

    float p[16], l[16];
#pragma unroll
    for (int i = 0; i < 16; ++i) {
        p[i] = 1.f / (1.f + expf(-e[i]));
        l[i] = logf(fmaxf(1.f - p[i], EPS_MOCHA));
    }
    float incl[16];
    incl[0] = l[0];
#pragma unroll
    for (int i = 1; i < 16; ++i) incl[i] = incl[i - 1] + l[i];
    float total = incl[15];
    float x = wave_incl_scan(total);
    float base = x - total;  // exclusive across lanes

    float o1[16], o2[16];
#pragma unroll
    for (int i = 0; i < 16; ++i) {
        float cl = base + (i ? incl[i - 1] : 0.f);
        float cp = expf(cl);
        o1[i] = p[i] * cp;
        o2[i] = 1.f / fmaxf(cp, EPS_MOCHA);
    }
    float* P = pcp + (size_t)row * 1024 + lane * 16;
    float* I = invcp + (size_t)row * 1024 + lane * 16;
    *(float4*)(P)      = *(float4*)&o1[0];
    *(float4*)(P + 4)  = *(float4*)&o1[4];
    *(float4*)(P + 8)  = *(float4*)&o1[8];
    *(float4*)(P + 12) = *(float4*)&o1[12];
    *(float4*)(I)      = *(float4*)&o2[0];
    *(float4*)(I + 4)  = *(float4*)&o2[4];
    *(float4*)(I + 8)  = *(float4*)&o2[8];
    *(float4*)(I + 12) = *(float4*)&o2[12];
}

// ---------------------------------------------------------------------------
// alpha_scan: one wave per (b,h), 16 k/lane, zero barriers, 4-deep prefetch,
// DPP wave scan on the serial chain.
// ---------------------------------------------------------------------------
__global__ __launch_bounds__(64) void alpha_scan(
    const float* __restrict__ pcp, const float* __restrict__ invcp,
    float* __restrict__ alpha)
{
    const int lane = threadIdx.x;
    const int bh = blockIdx.x;
    const float* P = pcp + (size_t)bh * 131072 + lane * 16;
    const float* I = invcp + (size_t)bh * 131072 + lane * 16;
    float* A = alpha + (size_t)bh * 131072 + lane * 16;

    float bp[4][16], bi[4][16];
#pragma unroll
    for (int s = 0; s < 4; ++s) {
        const float* Pq = P + (size_t)s * 1024;
        const float* Iq = I + (size_t)s * 1024;
        *(float4*)&bp[s][0]  = *(const float4*)(Pq);
        *(float4*)&bp[s][4]  = *(const float4*)(Pq + 4);
        *(float4*)&bp[s][8]  = *(const float4*)(Pq + 8);
        *(float4*)&bp[s][12] = *(const float4*)(Pq + 12);
        *(float4*)&bi[s][0]  = *(const float4*)(Iq);
        *(float4*)&bi[s][4]  = *(const float4*)(Iq + 4);
        *(float4*)&bi[s][8]  = *(const float4*)(Iq + 8);
        *(float4*)&bi[s][12] = *(const float4*)(Iq + 12);
    }

    float aw[16];
#pragma unroll
    for (int i = 0; i < 16; ++i) aw[i] = 0.f;
    if (lane == 0) aw[0] = 1.f;

    for (int q4 = 0; q4 < 128; q4 += 4) {
#pragma unroll
        for (int s = 0; s < 4; ++s) {
            const int q = q4 + s;
            float pc[16], ic[16];
#pragma unroll
            for (int i = 0; i < 16; ++i) { pc[i] = bp[s][i]; ic[i] = bi[s][i]; }
            if (q + 4 < 128) {
                const float* Pq = P + (size_t)(q + 4) * 1024;
                const float* Iq = I + (size_t)(q + 4) * 1024;
                *(float4*)&bp[s][0]  = *(const float4*)(Pq);
                *(float4*)&bp[s][4]  = *(const float4*)(Pq + 4);
                *(float4*)&bp[s][8]  = *(const float4*)(Pq + 8);
                *(float4*)&bp[s][12] = *(const float4*)(Pq + 12);
                *(float4*)&bi[s][0]  = *(const float4*)(Iq);
                *(float4*)&bi[s][4]  = *(const float4*)(Iq + 4);
                *(float4*)&bi[s][8]  = *(const float4*)(Iq + 8);
                *(float4*)&bi[s][12] = *(const float4*)(Iq + 12);
            }

            float incl[16];
            incl[0] = aw[0] * ic[0];
#pragma unroll
            for (int i = 1; i < 16; ++i) incl[i] = incl[i - 1] + aw[i] * ic[i];
            float total = incl[15];
            float x = wave_incl_scan(total);
            float base = x - total;
#pragma unroll
            for (int i = 0; i < 16; ++i) aw[i] = pc[i] * (base + incl[i]);

            float* Aq = A + (size_t)q * 1024;
            *(float4*)(Aq)      = *(float4*)&aw[0];
            *(float4*)(Aq + 4)  = *(float4*)&aw[4];
            *(float4*)(Aq + 8)  = *(float4*)&aw[8];
            *(float4*)(Aq + 12) = *(float4*)&aw[12];
        }
    }
}

// ---------------------------------------------------------------------------
// Beta -> fp16. One block per (b,q): all hc x hm in-block (alpha read once).
// LDS swizzle SW(k)=k+(k>>3). Grid: (q=128, b=8), 256 threads, 4 k each.
// ---------------------------------------------------------------------------
#define SW(k) ((k) + ((k) >> 3))

__global__ __launch_bounds__(256) void beta_kernel(
    const float* __restrict__ e_chunk, const float* __restrict__ alpha,
    _Float16* __restrict__ beta)
{
    __shared__ float sm[SW(1023) + 1];
    __shared__ float tm[SW(1027) + 1];
    __shared__ float red[4];
    const int q = blockIdx.x, b = blockIdx.y;
    const int tid = threadIdx.x;
    const int lane = tid & 63, wid = tid >> 6;
    const int k4 = tid * 4;

    float av[4][4];
#pragma unroll
    for (int hm = 0; hm < 4; ++hm)
        *(float4*)&av[hm][0] =
            *(const float4*)(alpha + (((size_t)b * 4 + hm) * 128 + q) * 1024 + k4);

    if (tid < 4) tm[SW(1024 + tid)] = 0.f;  // fwd-window zero pad (set once)

    for (int hc = 0; hc < 4; ++hc) {
        float4 ev = *(const float4*)(e_chunk + (((size_t)b * 4 + hc) * 128 + q) * 1024 + k4);
        float e[4] = {ev.x, ev.y, ev.z, ev.w};

        float mx = fmaxf(fmaxf(e[0], e[1]), fmaxf(e[2], e[3]));
#pragma unroll
        for (int off = 32; off >= 1; off >>= 1)
            mx = fmaxf(mx, __shfl_xor(mx, off, 64));
        if (lane == 0) red[wid] = mx;
        __syncthreads();
        mx = fmaxf(fmaxf(red[0], red[1]), fmaxf(red[2], red[3]));

        float sx[4];
#pragma unroll
        for (int i = 0; i < 4; ++i) {
            sx[i] = fmaxf(expf(e[i] - mx), 1e-5f);
            sm[SW(k4 + i)] = sx[i];
        }
        __syncthreads();

        float den[4];
#pragma unroll
        for (int i = 0; i < 4; ++i) {
            int k = k4 + i;
            float d = sm[SW(k)];
            if (k >= 1) d += sm[SW(k - 1)];
            if (k >= 2) d += sm[SW(k - 2)];
            if (k >= 3) d += sm[SW(k - 3)];
            den[i] = d;
        }

#pragma unroll
        for (int hm = 0; hm < 4; ++hm) {
            float t[4] = {av[hm][0] / den[0], av[hm][1] / den[1],
                          av[hm][2] / den[2], av[hm][3] / den[3]};
#pragma unroll
            for (int i = 0; i < 4; ++i) tm[SW(k4 + i)] = t[i];
            __syncthreads();
            float o[4];
#pragma unroll
            for (int i = 0; i < 4; ++i) {
                int k = k4 + i;
                float ms = tm[SW(k)] + tm[SW(k + 1)] + tm[SW(k + 2)] + tm[SW(k + 3)];
                o[i] = sx[i] * ms;
            }
            _Float16* Brow = beta + (((size_t)b * 16 + hm * 4 + hc) * 128 + q) * 1024;
            half4v hv = {(_Float16)o[0], (_Float16)o[1], (_Float16)o[2], (_Float16)o[3]};
            *(half4v*)(Brow + k4) = hv;
            __syncthreads();
        }
    }
}

// ---------------------------------------------------------------------------
// Context: cv[b,q,h*32+d] = sum_k beta16[b,h,q,k] * V[b,k,h*32+d]
// ---------------------------------------------------------------------------
__global__ __launch_bounds__(256) void context_kernel(
    const _Float16* __restrict__ beta, const float* __restrict__ V,
    float* __restrict__ cv)
{
    __shared__ float bS[32][64];
    __shared__ float vS[32][32];
    const int qh = blockIdx.x, h = blockIdx.y, b = blockIdx.z;
    const int tid = threadIdx.x;
    const int ty = tid >> 3, tx = tid & 7;
    const int q0 = qh * 64;

    const _Float16* Bbase = beta + (((size_t)b * 16 + h) * 128 + q0) * 1024;
    const float* Vbase = V + (size_t)b * 1024 * 512 + h * 32;

    float acc[2][4];
#pragma unroll
    for (int i = 0; i < 2; ++i)
#pragma unroll
        for (int j = 0; j < 4; ++j) acc[i][j] = 0.f;

    for (int k0 = 0; k0 < 1024; k0 += 32) {
        {
            int r = tid >> 2, c = tid & 3;
            half8 v = *(const half8*)(Bbase + (size_t)r * 1024 + k0 + c * 8);
#pragma unroll
            for (int j = 0; j < 8; ++j) bS[c * 8 + j][r] = (float)v[j];
        }
        {
            int kk = tid >> 3, c = tid & 7;
            float4 v = *(const float4*)(Vbase + (size_t)(k0 + kk) * 512 + c * 4);
            *(float4*)&vS[kk][c * 4] = v;
        }
        __syncthreads();
#pragma unroll
        for (int kk = 0; kk < 32; ++kk) {
            float a0 = bS[kk][ty * 2], a1 = bS[kk][ty * 2 + 1];
            float bb[4];
            *(float4*)bb = *(const float4*)&vS[kk][tx * 4];
#pragma unroll
            for (int j = 0; j < 4; ++j) {
                acc[0][j] = fmaf(a0, bb[j], acc[0][j]);
                acc[1][j] = fmaf(a1, bb[j], acc[1][j]);
            }
        }
        __syncthreads();
    }
#pragma unroll
    for (int i = 0; i < 2; ++i) {
        float* Cp = cv + ((size_t)b * 128 + q0 + ty * 2 + i) * 512 + h * 32 + tx * 4;
        *(float4*)Cp = make_float4(acc[i][0], acc[i][1], acc[i][2], acc[i][3]);
    }
}

// ---------------------------------------------------------------------------
extern "C" void kernel_launch(void* const* d_in, const int* in_sizes, int n_in,
                              void* d_out, int out_size, void* d_ws, size_t ws_size,
                              hipStream_t stream)
{
    const float* key_x   = (const float*)d_in[0];
    const float* query_x = (const float*)d_in[1];
    const int*   mask    = (const int*)d_in[2];
    const float* wk_m = (const float*)d_in[3];
    const float* bk_m = (const float*)d_in[4];
    const float* wq_m = (const float*)d_in[5];
    const float* bq_m = (const float*)d_in[6];
    const float* r    = (const float*)d_in[7];
    const float* wk_c = (const float*)d_in[8];
    const float* bk_c = (const float*)d_in[9];
    const float* wq_c = (const float*)d_in[10];
    const float* bq_c = (const float*)d_in[11];
    const float* wv   = (const float*)d_in[12];
    const float* bv   = (const float*)d_in[13];
    const float* wo   = (const float*)d_in[14];
    const float* bo   = (const float*)d_in[15];
    float* out = (float*)d_out;

    float* ws = (float*)d_ws;
    _Float16* hws = (_Float16*)d_ws;
    const size_t MEGF = 1024 * 1024;
    // Float-unit layout (fp16 offsets are 2x float offsets):
    //  phase A: K16 f[0,2), Q16 f[4,4.25), Wt5 f[4.5,5.25),
    //           Km16 f[6,8), Kc16 f[8,10), Qm16 f[10,10.125),
    //           Qc16 f[10.25,10.375), e_mono f[11,15), e_chunk f[15,19),
    //           V f[19,23), Wt_wo f[27.5,27.625)
    //  phase B (alpha): pcp = e_mono in-place; invcp f[0,4) (K16/Q16 dead);
    //           alpha f[23,27)
    //  phase C: beta16 f[0,8) (invcp/Km16/Kc16 dead), cv f[27,27.5)
    //  phase D: cv16 f[27.75,28). Peak 28 MEGF.
    _Float16* K16   = hws;                          // f 0
    _Float16* Q16   = hws + 8 * MEGF;               // f 4
    _Float16* Wt5   = hws + 9 * MEGF;               // f 4.5
    _Float16* Km16  = hws + 12 * MEGF;              // f 6
    _Float16* Kc16  = hws + 16 * MEGF;              // f 8
    _Float16* Qm16  = hws + 20 * MEGF;              // f 10
    _Float16* Qc16  = hws + 20 * MEGF + MEGF / 2;   // f 10.25
    float* e_mono  = ws + 11 * MEGF;
    float* pcp     = e_mono;                        // in-place
    float* invcp   = ws;                            // f 0 (over dead K16/Q16)
    float* e_chunk = ws + 15 * MEGF;
    float* V       = ws + 19 * MEGF;
    float* alpha   = ws + 23 * MEGF;
    _Float16* beta16 = hws;                         // f 0 (phase C overlay)
    float* cv      = ws + 27 * MEGF;
    _Float16* Wt_wo = hws + 55 * MEGF;              // f 27.5
    _Float16* cv16  = hws + 55 * MEGF + MEGF / 2;   // f 27.75

    // 0) merged prep: cvt key/query + pack 6 weights
    prep_kernel<<<dim3(4992), 256, 0, stream>>>(
        key_x, query_x, wk_m, wk_c, wv, wq_m, wq_c, wo,
        K16, Q16, Wt5, Wt_wo);
    // 1) key-side projections (M=8192): Km16 (f16), Kc16 (f16), V (f32)
    mfma_proj<<<dim3(64, 12), 256, 0, stream>>>(
        K16, Wt5, bk_m, Km16, bk_c, Kc16, bv, V, 0b011);
    // 2) query-side projections (M=1024): Qm16, Qc16 (f16)
    mfma_proj<<<dim3(8, 8), 256, 0, stream>>>(
        Q16, Wt5 + (size_t)3 * 262144, bq_m, Qm16, bq_c, Qc16, bq_c, Qc16, 0b011);
    // 3) both energies in one launch
    energy_mfma<<<dim3(8, 4, 16), 256, 0, stream>>>(
        Qm16, Km16, Qc16, Kc16, mask, e_mono, e_chunk, r);
    // 4) monotonic alpha: parallel transcendentals + DPP-scan recurrence
    alpha_pre<<<dim3(1024), 256, 0, stream>>>(e_mono, pcp, invcp);
    alpha_scan<<<dim3(32), 64, 0, stream>>>(pcp, invcp, alpha);
    // 5) chunkwise beta (fp16 out), one block per (b,q)
    beta_kernel<<<dim3(128, 8), 256, 0, stream>>>(e_chunk, alpha, beta16);
    // 6) context vectors
    context_kernel<<<dim3(2, 16, 8), 256, 0, stream>>>(beta16, V, cv);
    // 7) output projection via MFMA (M=1024, fp32 out)
    cvt_f32_f16<<<dim3(512), 256, 0, stream>>>(cv, cv16);
    mfma_proj<<<dim3(8, 4), 256, 0, stream>>>(
        cv16, Wt_wo, bo, out, bo, out, bo, out, 0b000);
}

// Round 12
// 289.038 us; speedup vs baseline: 1.3757x; 1.0108x over previous
//
#include <hip/hip_runtime.h>
#include <hip/hip_bf16.h>

// MoChA. Round 12: alpha_scan gets __launch_bounds__(64,1) (512-VGPR budget)
// + 8-deep prefetch (R11's depth-4 was silently demoted: VGPR_Count=104 <
// the 128 regs the buffers need -> effective depth ~1 -> latency-bound).
// Everything else unchanged from R11.
// B=8, Q=128, K=1024, D=512, HM=HC=4, CHUNK=4.

#define NEG_INF (-3.402823466e38f)
#define EPS_MOCHA 1e-6f
#define INV_SCALE 0.04419417382415922f  // 1/sqrt(512)

typedef _Float16 half8 __attribute__((ext_vector_type(8)));
typedef _Float16 half4v __attribute__((ext_vector_type(4)));
typedef float f32x4 __attribute__((ext_vector_type(4)));

#define ASTR 40  // LDS row stride in halfs (32 data + 8 pad; 80B, 16B-aligned)

// ---------------------------------------------------------------------------
// Wave64 inclusive add-scan via DPP (GCN classic): 6 VALU-latency steps.
// ---------------------------------------------------------------------------
__device__ __forceinline__ float wave_incl_scan(float x)
{
    int v;
    v = __builtin_amdgcn_update_dpp(0, __builtin_bit_cast(int, x), 0x111, 0xF, 0xF, false);
    x += __builtin_bit_cast(float, v);   // row_shr:1
    v = __builtin_amdgcn_update_dpp(0, __builtin_bit_cast(int, x), 0x112, 0xF, 0xF, false);
    x += __builtin_bit_cast(float, v);   // row_shr:2
    v = __builtin_amdgcn_update_dpp(0, __builtin_bit_cast(int, x), 0x114, 0xF, 0xF, false);
    x += __builtin_bit_cast(float, v);   // row_shr:4
    v = __builtin_amdgcn_update_dpp(0, __builtin_bit_cast(int, x), 0x118, 0xF, 0xF, false);
    x += __builtin_bit_cast(float, v);   // row_shr:8 -> row-inclusive
    v = __builtin_amdgcn_update_dpp(0, __builtin_bit_cast(int, x), 0x142, 0xA, 0xF, false);
    x += __builtin_bit_cast(float, v);   // row_bcast:15 -> rows 1,3
    v = __builtin_amdgcn_update_dpp(0, __builtin_bit_cast(int, x), 0x143, 0xC, 0xF, false);
    x += __builtin_bit_cast(float, v);   // row_bcast:31 -> rows 2,3
    return x;
}

// ---------------------------------------------------------------------------
// prep_kernel: one launch for all input packing.
//  blocks [0,4096): key_x -> K16 (fp16)
//  blocks [4096,4608): query_x -> Q16
//  blocks [4608,4992): transpose-pack 6 weights (wk_m,wk_c,wv,wq_m,wq_c,wo)
// ---------------------------------------------------------------------------
__global__ __launch_bounds__(256) void prep_kernel(
    const float* __restrict__ key_x, const float* __restrict__ query_x,
    const float* __restrict__ wk_m, const float* __restrict__ wk_c,
    const float* __restrict__ wv, const float* __restrict__ wq_m,
    const float* __restrict__ wq_c, const float* __restrict__ wo,
    _Float16* __restrict__ K16, _Float16* __restrict__ Q16,
    _Float16* __restrict__ Wt5, _Float16* __restrict__ Wt_wo)
{
    __shared__ float T[64][65];
    const int bid = blockIdx.x;
    const int t = threadIdx.x;
    if (bid < 4608) {
        const float* in = (bid < 4096) ? key_x : query_x;
        _Float16* out = (bid < 4096) ? K16 : Q16;
        const size_t i = (size_t)(bid < 4096 ? bid : bid - 4096) * 256 + t;
        float4 v = *(const float4*)(in + i * 4);
        half4v h = {(_Float16)v.x, (_Float16)v.y, (_Float16)v.z, (_Float16)v.w};
        *(half4v*)(out + i * 4) = h;
        return;
    }
    const int idx = bid - 4608;
    const int z = idx >> 6, tile = idx & 63;
    const float* W = (z == 0) ? wk_m : (z == 1) ? wk_c : (z == 2) ? wv
                   : (z == 3) ? wq_m : (z == 4) ? wq_c : wo;
    _Float16* O = (z < 5) ? (Wt5 + (size_t)z * 262144) : Wt_wo;
    const int n0 = (tile & 7) * 64, k0 = (tile >> 3) * 64;
    const int rr = t >> 4, cc = (t & 15) * 4;
#pragma unroll
    for (int r = 0; r < 4; ++r) {
        int k = r * 16 + rr;
        float4 v = *(const float4*)(W + (size_t)(k0 + k) * 512 + n0 + cc);
        T[k][cc + 0] = v.x; T[k][cc + 1] = v.y;
        T[k][cc + 2] = v.z; T[k][cc + 3] = v.w;
    }
    __syncthreads();
    const int nn = t >> 2, kc = (t & 3) * 16;
    _Float16 tmp[16];
#pragma unroll
    for (int i = 0; i < 16; ++i) tmp[i] = (_Float16)T[kc + i][nn];
    _Float16* Op = O + (size_t)(n0 + nn) * 512 + k0 + kc;
    *(half8*)(Op)     = *(half8*)&tmp[0];
    *(half8*)(Op + 8) = *(half8*)&tmp[8];
}

// ---------------------------------------------------------------------------
// cvt: fp32 -> fp16 (cv -> cv16).
// ---------------------------------------------------------------------------
__global__ __launch_bounds__(256) void cvt_f32_f16(
    const float* __restrict__ in, _Float16* __restrict__ out)
{
    const size_t i = (size_t)blockIdx.x * 256 + threadIdx.x;
    float4 v = *(const float4*)(in + i * 4);
    half4v h = {(_Float16)v.x, (_Float16)v.y, (_Float16)v.z, (_Float16)v.w};
    *(half4v*)(out + i * 4) = h;
}

__device__ __forceinline__ void mfma_step(half8 a[4], half8 b[4], f32x4 acc[4][4])
{
#pragma unroll
    for (int mt = 0; mt < 4; ++mt)
#pragma unroll
        for (int nt = 0; nt < 4; ++nt)
            acc[mt][nt] = __builtin_amdgcn_mfma_f32_16x16x32_f16(
                a[mt], b[nt], acc[mt][nt], 0, 0, 0);
}

// ---------------------------------------------------------------------------
// MFMA projection GEMM (LDS-staged): C[m][n] = sum_k A16[m][k]*Wt[n][k]+bias.
// Block 256 = 2x2 waves, tile 128x128, wave 64x64 (4x4 frags), BK=32.
// f16_mask bit g: C stored fp16. Grid: (M/128, ngroups*4).
// ---------------------------------------------------------------------------
__global__ __launch_bounds__(256) void mfma_proj(
    const _Float16* __restrict__ A16, const _Float16* __restrict__ Wt_base,
    const float* __restrict__ bias0, void* __restrict__ C0,
    const float* __restrict__ bias1, void* __restrict__ C1,
    const float* __restrict__ bias2, void* __restrict__ C2,
    int f16_mask)
{
    __shared__ _Float16 As[128 * ASTR];
    __shared__ _Float16 Bs[128 * ASTR];
    const int tid = threadIdx.x;
    const int lane = tid & 63, wave = tid >> 6;
    const int wm = wave >> 1, wn = wave & 1;
    const int col = lane & 15, quad = lane >> 4;
    const int g = blockIdx.y >> 2, nt128 = blockIdx.y & 3;
    const _Float16* Wt = Wt_base + (size_t)g * 262144;
    const float* bias = (g == 0) ? bias0 : (g == 1) ? bias1 : bias2;
    void*        Cv   = (g == 0) ? C0    : (g == 1) ? C1    : C2;
    const int f16o = (f16_mask >> g) & 1;
    const int m0 = blockIdx.x * 128, n0 = nt128 * 128;

    const int srow = tid >> 1, sseg = tid & 1;
    const _Float16* Ag = A16 + (size_t)(m0 + srow) * 512 + sseg * 16;
    const _Float16* Bg = Wt  + (size_t)(n0 + srow) * 512 + sseg * 16;
    _Float16* Al = As + srow * ASTR + sseg * 16;
    _Float16* Bl = Bs + srow * ASTR + sseg * 16;

    f32x4 acc[4][4];
#pragma unroll
    for (int mt = 0; mt < 4; ++mt)
#pragma unroll
        for (int nt = 0; nt < 4; ++nt) acc[mt][nt] = (f32x4)0.f;

    const _Float16* Afr = As + (size_t)(wm * 64 + col) * ASTR + quad * 8;
    const _Float16* Bfr = Bs + (size_t)(wn * 64 + col) * ASTR + quad * 8;

    half8 pa0, pa1, pb0, pb1;
    pa0 = *(const half8*)(Ag);
    pa1 = *(const half8*)(Ag + 8);
    pb0 = *(const half8*)(Bg);
    pb1 = *(const half8*)(Bg + 8);

    for (int ks = 0; ks < 16; ++ks) {
        __syncthreads();
        *(half8*)(Al)     = pa0;
        *(half8*)(Al + 8) = pa1;
        *(half8*)(Bl)     = pb0;
        *(half8*)(Bl + 8) = pb1;
        __syncthreads();
        if (ks + 1 < 16) {
            const int k0 = (ks + 1) * 32;
            pa0 = *(const half8*)(Ag + k0);
            pa1 = *(const half8*)(Ag + k0 + 8);
            pb0 = *(const half8*)(Bg + k0);
            pb1 = *(const half8*)(Bg + k0 + 8);
        }
        half8 a[4], b[4];
#pragma unroll
        for (int t = 0; t < 4; ++t) {
            a[t] = *(const half8*)(Afr + (size_t)t * 16 * ASTR);
            b[t] = *(const half8*)(Bfr + (size_t)t * 16 * ASTR);
        }
        mfma_step(a, b, acc);
    }

    float bnt[4];
#pragma unroll
    for (int nt = 0; nt < 4; ++nt)
        bnt[nt] = bias[n0 + wn * 64 + nt * 16 + col];
#pragma unroll
    for (int mt = 0; mt < 4; ++mt) {
        const int rowb = m0 + wm * 64 + mt * 16 + quad * 4;
#pragma unroll
        for (int nt = 0; nt < 4; ++nt) {
            const int cc = n0 + wn * 64 + nt * 16 + col;
#pragma unroll
            for (int r = 0; r < 4; ++r) {
                float v = acc[mt][nt][r] + bnt[nt];
                if (f16o)
                    ((_Float16*)Cv)[(size_t)(rowb + r) * 512 + cc] = (_Float16)v;
                else
                    ((float*)Cv)[(size_t)(rowb + r) * 512 + cc] = v;
            }
        }
    }
}

// ---------------------------------------------------------------------------
// Energy via MFMA, both heads in one launch (direct-global frags, K=128).
// Grid: (kt=8, h=4, z=16); z<8: mono (b=z, +r, e_mono); z>=8: chunk.
// ---------------------------------------------------------------------------
__device__ __forceinline__ void load_frags_g(
    const _Float16* Ap, const _Float16* Bp, int kk, half8 a[4], half8 b[4])
{
#pragma unroll
    for (int t = 0; t < 4; ++t) {
        a[t] = *(const half8*)(Ap + (size_t)t * 16 * 512 + kk);
        b[t] = *(const half8*)(Bp + (size_t)t * 16 * 512 + kk);
    }
}

__global__ __launch_bounds__(256) void energy_mfma(
    const _Float16* __restrict__ Qm, const _Float16* __restrict__ Km,
    const _Float16* __restrict__ Qc, const _Float16* __restrict__ Kc,
    const int* __restrict__ mask, float* __restrict__ e_mono,
    float* __restrict__ e_chunk, const float* __restrict__ r_ptr)
{
    const int tid = threadIdx.x;
    const int lane = tid & 63, wave = tid >> 6;
    const int wm = wave >> 1, wn = wave & 1;
    const int col = lane & 15, quad = lane >> 4;
    const int kt0 = blockIdx.x * 128;
    const int h = blockIdx.y;
    const int z = blockIdx.z;
    const int b = z & 7;
    const bool mono = z < 8;
    const _Float16* Qp = mono ? Qm : Qc;
    const _Float16* Kp = mono ? Km : Kc;
    float* out = mono ? e_mono : e_chunk;
    const float rv = mono ? r_ptr[0] : 0.f;

    const _Float16* Ap = Qp + (size_t)(b * 128 + wm * 64 + col) * 512 + h * 128 + quad * 8;
    const _Float16* Bp = Kp + (size_t)(b * 1024 + kt0 + wn * 64 + col) * 512 + h * 128 + quad * 8;

    f32x4 acc[4][4];
#pragma unroll
    for (int mt = 0; mt < 4; ++mt)
#pragma unroll
        for (int nt = 0; nt < 4; ++nt) acc[mt][nt] = (f32x4)0.f;

    half8 ab[3][4], bb[3][4];
    load_frags_g(Ap, Bp, 0, ab[0], bb[0]);
    load_frags_g(Ap, Bp, 32, ab[1], bb[1]);
#pragma unroll
    for (int ks = 0; ks < 4; ++ks) {
        const int cur = ks % 3, nxt = (ks + 2) % 3;
        if (ks + 2 < 4)
            load_frags_g(Ap, Bp, (ks + 2) * 32, ab[nxt], bb[nxt]);
        mfma_step(ab[cur], bb[cur], acc);
    }

#pragma unroll
    for (int mt = 0; mt < 4; ++mt) {
        const int qb = wm * 64 + mt * 16 + quad * 4;
#pragma unroll
        for (int nt = 0; nt < 4; ++nt) {
            const int kc = kt0 + wn * 64 + nt * 16 + col;
#pragma unroll
            for (int r = 0; r < 4; ++r) {
                const int q = qb + r;
                float v = acc[mt][nt][r] * INV_SCALE + rv;
                int mv = mask[((size_t)b * 128 + q) * 1024 + kc];
                out[(((size_t)b * 4 + h) * 128 + q) * 1024 + kc] = mv ? v : NEG_INF;
            }
        }
    }
}

// ---------------------------------------------------------------------------
// alpha_pre: parallel part of the monotonic recurrence (one wave per row).
// ---------------------------------------------------------------------------
__global__ __launch_bounds__(256) void alpha_pre(
    const float* __restrict__ e_mono, float* __restrict__ pcp,
    float* __restrict__ invcp)
{
    const int tid = threadIdx.x;
    const int lane = tid & 63;
    const int row = blockIdx.x * 4 + (tid >> 6);
    const float* E = e_mono + (size_t)row * 1024 + lane * 16;

    float e[16];
    *(float4*)&e[0]  = *(const float4*)(E);
    *(float4*)&e[4]  = *(const float4*)(E + 4);
    *(float4*)&e[8]  = *(const float4*)(E + 8);
    *(float4*)&e[12] = *(const float4*)(E + 12);

    float p[16], l[16];
#pragma unroll
    for (int i = 0; i < 16; ++i) {
        p[i] = 1.f / (1.f + expf(-e[i]));
        l[i] = logf(fmaxf(1.f - p[i], EPS_MOCHA));
    }
    float incl[16];
    incl[0] = l[0];
#pragma unroll
    for (int i = 1; i < 16; ++i) incl[i] = incl[i - 1] + l[i];
    float total = incl[15];
    float x = wave_incl_scan(total);
    float base = x - total;  // exclusive across lanes

    float o1[16], o2[16];
#pragma unroll
    for (int i = 0; i < 16; ++i) {
        float cl = base + (i ? incl[i - 1] : 0.f);
        float cp = expf(cl);
        o1[i] = p[i] * cp;
        o2[i] = 1.f / fmaxf(cp, EPS_MOCHA);
    }
    float* P = pcp + (size_t)row * 1024 + lane * 16;
    float* I = invcp + (size_t)row * 1024 + lane * 16;
    *(float4*)(P)      = *(float4*)&o1[0];
    *(float4*)(P + 4)  = *(float4*)&o1[4];
    *(float4*)(P + 8)  = *(float4*)&o1[8];
    *(float4*)(P + 12) = *(float4*)&o1[12];
    *(float4*)(I)      = *(float4*)&o2[0];
    *(float4*)(I + 4)  = *(float4*)&o2[4];
    *(float4*)(I + 8)  = *(float4*)&o2[8];
    *(float4*)(I + 12) = *(float4*)&o2[12];
}

// ---------------------------------------------------------------------------
// alpha_scan: one wave per (b,h), 16 k/lane, zero barriers, 8-deep prefetch
// (launch_bounds(64,1) -> 512-VGPR budget keeps all slots resident),
// DPP wave scan on the serial chain.
// ---------------------------------------------------------------------------
__global__ __launch_bounds__(64, 1) void alpha_scan(
    const float* __restrict__ pcp, const float* __restrict__ invcp,
    float* __restrict__ alpha)
{
    const int lane = threadIdx.x;
    const int bh = blockIdx.x;
    const float* P = pcp + (size_t)bh * 131072 + lane * 16;
    const float* I = invcp + (size_t)bh * 131072 + lane * 16;
    float* A = alpha + (size_t)bh * 131072 + lane * 16;

    float bp[8][16], bi[8][16];
#pragma unroll
    for (int s = 0; s < 8; ++s) {
        const float* Pq = P + (size_t)s * 1024;
        const float* Iq = I + (size_t)s * 1024;
        *(float4*)&bp[s][0]  = *(const float4*)(Pq);
        *(float4*)&bp[s][4]  = *(const float4*)(Pq + 4);
        *(float4*)&bp[s][8]  = *(const float4*)(Pq + 8);
        *(float4*)&bp[s][12] = *(const float4*)(Pq + 12);
        *(float4*)&bi[s][0]  = *(const float4*)(Iq);
        *(float4*)&bi[s][4]  = *(const float4*)(Iq + 4);
        *(float4*)&bi[s][8]  = *(const float4*)(Iq + 8);
        *(float4*)&bi[s][12] = *(const float4*)(Iq + 12);
    }

    float aw[16];
#pragma unroll
    for (int i = 0; i < 16; ++i) aw[i] = 0.f;
    if (lane == 0) aw[0] = 1.f;

    for (int q8 = 0; q8 < 128; q8 += 8) {
#pragma unroll
        for (int s = 0; s < 8; ++s) {
            const int q = q8 + s;
            float pc[16], ic[16];
#pragma unroll
            for (int i = 0; i < 16; ++i) { pc[i] = bp[s][i]; ic[i] = bi[s][i]; }
            if (q + 8 < 128) {  // refill slot s for q+8 (issues before chain)
                const float* Pq = P + (size_t)(q + 8) * 1024;
                const float* Iq = I + (size_t)(q + 8) * 1024;
                *(float4*)&bp[s][0]  = *(const float4*)(Pq);
                *(float4*)&bp[s][4]  = *(const float4*)(Pq + 4);
                *(float4*)&bp[s][8]  = *(const float4*)(Pq + 8);
                *(float4*)&bp[s][12] = *(const float4*)(Pq + 12);
                *(float4*)&bi[s][0]  = *(const float4*)(Iq);
                *(float4*)&bi[s][4]  = *(const float4*)(Iq + 4);
                *(float4*)&bi[s][8]  = *(const float4*)(Iq + 8);
                *(float4*)&bi[s][12] = *(const float4*)(Iq + 12);
            }

            float incl[16];
            incl[0] = aw[0] * ic[0];
#pragma unroll
            for (int i = 1; i < 16; ++i) incl[i] = incl[i - 1] + aw[i] * ic[i];
            float total = incl[15];
            float x = wave_incl_scan(total);
            float base = x - total;  // exclusive across lanes
#pragma unroll
            for (int i = 0; i < 16; ++i) aw[i] = pc[i] * (base + incl[i]);

            float* Aq = A + (size_t)q * 1024;
            *(float4*)(Aq)      = *(float4*)&aw[0];
            *(float4*)(Aq + 4)  = *(float4*)&aw[4];
            *(float4*)(Aq + 8)  = *(float4*)&aw[8];
            *(float4*)(Aq + 12) = *(float4*)&aw[12];
        }
    }
}

// ---------------------------------------------------------------------------
// Beta -> fp16. One block per (b,q): all hc x hm in-block (alpha read once).
// LDS swizzle SW(k)=k+(k>>3). Grid: (q=128, b=8), 256 threads, 4 k each.
// ---------------------------------------------------------------------------
#define SW(k) ((k) + ((k) >> 3))

__global__ __launch_bounds__(256) void beta_kernel(
    const float* __restrict__ e_chunk, const float* __restrict__ alpha,
    _Float16* __restrict__ beta)
{
    __shared__ float sm[SW(1023) + 1];
    __shared__ float tm[SW(1027) + 1];
    __shared__ float red[4];
    const int q = blockIdx.x, b = blockIdx.y;
    const int tid = threadIdx.x;
    const int lane = tid & 63, wid = tid >> 6;
    const int k4 = tid * 4;

    float av[4][4];
#pragma unroll
    for (int hm = 0; hm < 4; ++hm)
        *(float4*)&av[hm][0] =
            *(const float4*)(alpha + (((size_t)b * 4 + hm) * 128 + q) * 1024 + k4);

    if (tid < 4) tm[SW(1024 + tid)] = 0.f;  // fwd-window zero pad (set once)

    for (int hc = 0; hc < 4; ++hc) {
        float4 ev = *(const float4*)(e_chunk + (((size_t)b * 4 + hc) * 128 + q) * 1024 + k4);
        float e[4] = {ev.x, ev.y, ev.z, ev.w};

        float mx = fmaxf(fmaxf(e[0], e[1]), fmaxf(e[2], e[3]));
#pragma unroll
        for (int off = 32; off >= 1; off >>= 1)
            mx = fmaxf(mx, __shfl_xor(mx, off, 64));
        if (lane == 0) red[wid] = mx;
        __syncthreads();
        mx = fmaxf(fmaxf(red[0], red[1]), fmaxf(red[2], red[3]));

        float sx[4];
#pragma unroll
        for (int i = 0; i < 4; ++i) {
            sx[i] = fmaxf(expf(e[i] - mx), 1e-5f);
            sm[SW(k4 + i)] = sx[i];
        }
        __syncthreads();

        float den[4];
#pragma unroll
        for (int i = 0; i < 4; ++i) {
            int k = k4 + i;
            float d = sm[SW(k)];
            if (k >= 1) d += sm[SW(k - 1)];
            if (k >= 2) d += sm[SW(k - 2)];
            if (k >= 3) d += sm[SW(k - 3)];
            den[i] = d;
        }

#pragma unroll
        for (int hm = 0; hm < 4; ++hm) {
            float t[4] = {av[hm][0] / den[0], av[hm][1] / den[1],
                          av[hm][2] / den[2], av[hm][3] / den[3]};
#pragma unroll
            for (int i = 0; i < 4; ++i) tm[SW(k4 + i)] = t[i];
            __syncthreads();
            float o[4];
#pragma unroll
            for (int i = 0; i < 4; ++i) {
                int k = k4 + i;
                float ms = tm[SW(k)] + tm[SW(k + 1)] + tm[SW(k + 2)] + tm[SW(k + 3)];
                o[i] = sx[i] * ms;
            }
            _Float16* Brow = beta + (((size_t)b * 16 + hm * 4 + hc) * 128 + q) * 1024;
            half4v hv = {(_Float16)o[0], (_Float16)o[1], (_Float16)o[2], (_Float16)o[3]};
            *(half4v*)(Brow + k4) = hv;
            __syncthreads();
        }
    }
}

// ---------------------------------------------------------------------------
// Context: cv[b,q,h*32+d] = sum_k beta16[b,h,q,k] * V[b,k,h*32+d]
// ---------------------------------------------------------------------------
__global__ __launch_bounds__(256) void context_kernel(
    const _Float16* __restrict__ beta, const float* __restrict__ V,
    float* __restrict__ cv)
{
    __shared__ float bS[32][64];
    __shared__ float vS[32][32];
    const int qh = blockIdx.x, h = blockIdx.y, b = blockIdx.z;
    const int tid = threadIdx.x;
    const int ty = tid >> 3, tx = tid & 7;
    const int q0 = qh * 64;

    const _Float16* Bbase = beta + (((size_t)b * 16 + h) * 128 + q0) * 1024;
    const float* Vbase = V + (size_t)b * 1024 * 512 + h * 32;

    float acc[2][4];
#pragma unroll
    for (int i = 0; i < 2; ++i)
#pragma unroll
        for (int j = 0; j < 4; ++j) acc[i][j] = 0.f;

    for (int k0 = 0; k0 < 1024; k0 += 32) {
        {
            int r = tid >> 2, c = tid & 3;
            half8 v = *(const half8*)(Bbase + (size_t)r * 1024 + k0 + c * 8);
#pragma unroll
            for (int j = 0; j < 8; ++j) bS[c * 8 + j][r] = (float)v[j];
        }
        {
            int kk = tid >> 3, c = tid & 7;
            float4 v = *(const float4*)(Vbase + (size_t)(k0 + kk) * 512 + c * 4);
            *(float4*)&vS[kk][c * 4] = v;
        }
        __syncthreads();
#pragma unroll
        for (int kk = 0; kk < 32; ++kk) {
            float a0 = bS[kk][ty * 2], a1 = bS[kk][ty * 2 + 1];
            float bb[4];
            *(float4*)bb = *(const float4*)&vS[kk][tx * 4];
#pragma unroll
            for (int j = 0; j < 4; ++j) {
                acc[0][j] = fmaf(a0, bb[j], acc[0][j]);
                acc[1][j] = fmaf(a1, bb[j], acc[1][j]);
            }
        }
        __syncthreads();
    }
#pragma unroll
    for (int i = 0; i < 2; ++i) {
        float* Cp = cv + ((size_t)b * 128 + q0 + ty * 2 + i) * 512 + h * 32 + tx * 4;
        *(float4*)Cp = make_float4(acc[i][0], acc[i][1], acc[i][2], acc[i][3]);
    }
}

// ---------------------------------------------------------------------------
extern "C" void kernel_launch(void* const* d_in, const int* in_sizes, int n_in,
                              void* d_out, int out_size, void* d_ws, size_t ws_size,
                              hipStream_t stream)
{
    const float* key_x   = (const float*)d_in[0];
    const float* query_x = (const float*)d_in[1];
    const int*   mask    = (const int*)d_in[2];
    const float* wk_m = (const float*)d_in[3];
    const float* bk_m = (const float*)d_in[4];
    const float* wq_m = (const float*)d_in[5];
    const float* bq_m = (const float*)d_in[6];
    const float* r    = (const float*)d_in[7];
    const float* wk_c = (const float*)d_in[8];
    const float* bk_c = (const float*)d_in[9];
    const float* wq_c = (const float*)d_in[10];
    const float* bq_c = (const float*)d_in[11];
    const float* wv   = (const float*)d_in[12];
    const float* bv   = (const float*)d_in[13];
    const float* wo   = (const float*)d_in[14];
    const float* bo   = (const float*)d_in[15];
    float* out = (float*)d_out;

    float* ws = (float*)d_ws;
    _Float16* hws = (_Float16*)d_ws;
    const size_t MEGF = 1024 * 1024;
    // Float-unit layout (fp16 offsets are 2x float offsets):
    //  phase A: K16 f[0,2), Q16 f[4,4.25), Wt5 f[4.5,5.25),
    //           Km16 f[6,8), Kc16 f[8,10), Qm16 f[10,10.125),
    //           Qc16 f[10.25,10.375), e_mono f[11,15), e_chunk f[15,19),
    //           V f[19,23), Wt_wo f[27.5,27.625)
    //  phase B (alpha): pcp = e_mono in-place; invcp f[0,4) (K16/Q16 dead);
    //           alpha f[23,27)
    //  phase C: beta16 f[0,8) (invcp/Km16/Kc16 dead), cv f[27,27.5)
    //  phase D: cv16 f[27.75,28). Peak 28 MEGF.
    _Float16* K16   = hws;                          // f 0
    _Float16* Q16   = hws + 8 * MEGF;               // f 4
    _Float16* Wt5   = hws + 9 * MEGF;               // f 4.5
    _Float16* Km16  = hws + 12 * MEGF;              // f 6
    _Float16* Kc16  = hws + 16 * MEGF;              // f 8
    _Float16* Qm16  = hws + 20 * MEGF;              // f 10
    _Float16* Qc16  = hws + 20 * MEGF + MEGF / 2;   // f 10.25
    float* e_mono  = ws + 11 * MEGF;
    float* pcp     = e_mono;                        // in-place
    float* invcp   = ws;                            // f 0 (over dead K16/Q16)
    float* e_chunk = ws + 15 * MEGF;
    float* V       = ws + 19 * MEGF;
    float* alpha   = ws + 23 * MEGF;
    _Float16* beta16 = hws;                         // f 0 (phase C overlay)
    float* cv      = ws + 27 * MEGF;
    _Float16* Wt_wo = hws + 55 * MEGF;              // f 27.5
    _Float16* cv16  = hws + 55 * MEGF + MEGF / 2;   // f 27.75

    // 0) merged prep: cvt key/query + pack 6 weights
    prep_kernel<<<dim3(4992), 256, 0, stream>>>(
        key_x, query_x, wk_m, wk_c, wv, wq_m, wq_c, wo,
        K16, Q16, Wt5, Wt_wo);
    // 1) key-side projections (M=8192): Km16 (f16), Kc16 (f16), V (f32)
    mfma_proj<<<dim3(64, 12), 256, 0, stream>>>(
        K16, Wt5, bk_m, Km16, bk_c, Kc16, bv, V, 0b011);
    // 2) query-side projections (M=1024): Qm16, Qc16 (f16)
    mfma_proj<<<dim3(8, 8), 256, 0, stream>>>(
        Q16, Wt5 + (size_t)3 * 262144, bq_m, Qm16, bq_c, Qc16, bq_c, Qc16, 0b011);
    // 3) both energies in one launch
    energy_mfma<<<dim3(8, 4, 16), 256, 0, stream>>>(
        Qm16, Km16, Qc16, Kc16, mask, e_mono, e_chunk, r);
    // 4) monotonic alpha: parallel transcendentals + 8-deep DPP-scan
    alpha_pre<<<dim3(1024), 256, 0, stream>>>(e_mono, pcp, invcp);
    alpha_scan<<<dim3(32), 64, 0, stream>>>(pcp, invcp, alpha);
    // 5) chunkwise beta (fp16 out), one block per (b,q)
    beta_kernel<<<dim3(128, 8), 256, 0, stream>>>(e_chunk, alpha, beta16);
    // 6) context vectors
    context_kernel<<<dim3(2, 16, 8), 256, 0, stream>>>(beta16, V, cv);
    // 7) output projection via MFMA (M=1024, fp32 out)
    cvt_f32_f16<<<dim3(512), 256, 0, stream>>>(cv, cv16);
    mfma_proj<<<dim3(8, 4), 256, 0, stream>>>(
        cv16, Wt_wo, bo, out, bo, out, bo, out, 0b000);
}

// Round 13
// 272.082 us; speedup vs baseline: 1.4615x; 1.0623x over previous
//
#include <hip/hip_runtime.h>
#include <hip/hip_bf16.h>

// MoChA. Round 13: (1) alpha recurrence refactored to single-stream scan:
// G_q = pcp_{q-1} * invcp_q precomputed in alpha_pre; scan iterates
// S_q = cumsum(G_q * S_{q-1}) (16MB stream, 4 loads/step, 8-deep = 128 VGPR
// buffer the compiler can actually keep); beta applies aw = pcp * S.
// (2) context writes cv16 directly (cvt dispatch removed). (3) key+query
// projections merged into one 5-group launch. 8 dispatches total.
// B=8, Q=128, K=1024, D=512, HM=HC=4, CHUNK=4.

#define NEG_INF (-3.402823466e38f)
#define EPS_MOCHA 1e-6f
#define INV_SCALE 0.04419417382415922f  // 1/sqrt(512)

typedef _Float16 half8 __attribute__((ext_vector_type(8)));
typedef _Float16 half4v __attribute__((ext_vector_type(4)));
typedef float f32x4 __attribute__((ext_vector_type(4)));

#define ASTR 40  // LDS row stride in halfs (32 data + 8 pad; 80B, 16B-aligned)

// ---------------------------------------------------------------------------
// Wave64 inclusive add-scan via DPP: 6 VALU-latency steps.
// ---------------------------------------------------------------------------
__device__ __forceinline__ float wave_incl_scan(float x)
{
    int v;
    v = __builtin_amdgcn_update_dpp(0, __builtin_bit_cast(int, x), 0x111, 0xF, 0xF, false);
    x += __builtin_bit_cast(float, v);   // row_shr:1
    v = __builtin_amdgcn_update_dpp(0, __builtin_bit_cast(int, x), 0x112, 0xF, 0xF, false);
    x += __builtin_bit_cast(float, v);   // row_shr:2
    v = __builtin_amdgcn_update_dpp(0, __builtin_bit_cast(int, x), 0x114, 0xF, 0xF, false);
    x += __builtin_bit_cast(float, v);   // row_shr:4
    v = __builtin_amdgcn_update_dpp(0, __builtin_bit_cast(int, x), 0x118, 0xF, 0xF, false);
    x += __builtin_bit_cast(float, v);   // row_shr:8 -> row-inclusive
    v = __builtin_amdgcn_update_dpp(0, __builtin_bit_cast(int, x), 0x142, 0xA, 0xF, false);
    x += __builtin_bit_cast(float, v);   // row_bcast:15 -> rows 1,3
    v = __builtin_amdgcn_update_dpp(0, __builtin_bit_cast(int, x), 0x143, 0xC, 0xF, false);
    x += __builtin_bit_cast(float, v);   // row_bcast:31 -> rows 2,3
    return x;
}

// ---------------------------------------------------------------------------
// prep_kernel: one launch for all input packing.
// ---------------------------------------------------------------------------
__global__ __launch_bounds__(256) void prep_kernel(
    const float* __restrict__ key_x, const float* __restrict__ query_x,
    const float* __restrict__ wk_m, const float* __restrict__ wk_c,
    const float* __restrict__ wv, const float* __restrict__ wq_m,
    const float* __restrict__ wq_c, const float* __restrict__ wo,
    _Float16* __restrict__ K16, _Float16* __restrict__ Q16,
    _Float16* __restrict__ Wt5, _Float16* __restrict__ Wt_wo)
{
    __shared__ float T[64][65];
    const int bid = blockIdx.x;
    const int t = threadIdx.x;
    if (bid < 4608) {
        const float* in = (bid < 4096) ? key_x : query_x;
        _Float16* out = (bid < 4096) ? K16 : Q16;
        const size_t i = (size_t)(bid < 4096 ? bid : bid - 4096) * 256 + t;
        float4 v = *(const float4*)(in + i * 4);
        half4v h = {(_Float16)v.x, (_Float16)v.y, (_Float16)v.z, (_Float16)v.w};
        *(half4v*)(out + i * 4) = h;
        return;
    }
    const int idx = bid - 4608;
    const int z = idx >> 6, tile = idx & 63;
    const float* W = (z == 0) ? wk_m : (z == 1) ? wk_c : (z == 2) ? wv
                   : (z == 3) ? wq_m : (z == 4) ? wq_c : wo;
    _Float16* O = (z < 5) ? (Wt5 + (size_t)z * 262144) : Wt_wo;
    const int n0 = (tile & 7) * 64, k0 = (tile >> 3) * 64;
    const int rr = t >> 4, cc = (t & 15) * 4;
#pragma unroll
    for (int r = 0; r < 4; ++r) {
        int k = r * 16 + rr;
        float4 v = *(const float4*)(W + (size_t)(k0 + k) * 512 + n0 + cc);
        T[k][cc + 0] = v.x; T[k][cc + 1] = v.y;
        T[k][cc + 2] = v.z; T[k][cc + 3] = v.w;
    }
    __syncthreads();
    const int nn = t >> 2, kc = (t & 3) * 16;
    _Float16 tmp[16];
#pragma unroll
    for (int i = 0; i < 16; ++i) tmp[i] = (_Float16)T[kc + i][nn];
    _Float16* Op = O + (size_t)(n0 + nn) * 512 + k0 + kc;
    *(half8*)(Op)     = *(half8*)&tmp[0];
    *(half8*)(Op + 8) = *(half8*)&tmp[8];
}

__device__ __forceinline__ void mfma_step(half8 a[4], half8 b[4], f32x4 acc[4][4])
{
#pragma unroll
    for (int mt = 0; mt < 4; ++mt)
#pragma unroll
        for (int nt = 0; nt < 4; ++nt)
            acc[mt][nt] = __builtin_amdgcn_mfma_f32_16x16x32_f16(
                a[mt], b[nt], acc[mt][nt], 0, 0, 0);
}

// ---------------------------------------------------------------------------
// LDS-staged GEMM core: 128x128 tile, BK=32, 2x2 waves, 16 K-steps.
// ---------------------------------------------------------------------------
__device__ __forceinline__ void gemm_core(
    const _Float16* __restrict__ A16, const _Float16* __restrict__ Wt,
    _Float16* As, _Float16* Bs, int m0, int n0,
    const float* __restrict__ bias, void* __restrict__ Cv, int f16o)
{
    const int tid = threadIdx.x;
    const int lane = tid & 63, wave = tid >> 6;
    const int wm = wave >> 1, wn = wave & 1;
    const int col = lane & 15, quad = lane >> 4;

    const int srow = tid >> 1, sseg = tid & 1;
    const _Float16* Ag = A16 + (size_t)(m0 + srow) * 512 + sseg * 16;
    const _Float16* Bg = Wt  + (size_t)(n0 + srow) * 512 + sseg * 16;
    _Float16* Al = As + srow * ASTR + sseg * 16;
    _Float16* Bl = Bs + srow * ASTR + sseg * 16;

    f32x4 acc[4][4];
#pragma unroll
    for (int mt = 0; mt < 4; ++mt)
#pragma unroll
        for (int nt = 0; nt < 4; ++nt) acc[mt][nt] = (f32x4)0.f;

    const _Float16* Afr = As + (size_t)(wm * 64 + col) * ASTR + quad * 8;
    const _Float16* Bfr = Bs + (size_t)(wn * 64 + col) * ASTR + quad * 8;

    half8 pa0, pa1, pb0, pb1;
    pa0 = *(const half8*)(Ag);
    pa1 = *(const half8*)(Ag + 8);
    pb0 = *(const half8*)(Bg);
    pb1 = *(const half8*)(Bg + 8);

    for (int ks = 0; ks < 16; ++ks) {
        __syncthreads();
        *(half8*)(Al)     = pa0;
        *(half8*)(Al + 8) = pa1;
        *(half8*)(Bl)     = pb0;
        *(half8*)(Bl + 8) = pb1;
        __syncthreads();
        if (ks + 1 < 16) {
            const int k0 = (ks + 1) * 32;
            pa0 = *(const half8*)(Ag + k0);
            pa1 = *(const half8*)(Ag + k0 + 8);
            pb0 = *(const half8*)(Bg + k0);
            pb1 = *(const half8*)(Bg + k0 + 8);
        }
        half8 a[4], b[4];
#pragma unroll
        for (int t = 0; t < 4; ++t) {
            a[t] = *(const half8*)(Afr + (size_t)t * 16 * ASTR);
            b[t] = *(const half8*)(Bfr + (size_t)t * 16 * ASTR);
        }
        mfma_step(a, b, acc);
    }

    float bnt[4];
#pragma unroll
    for (int nt = 0; nt < 4; ++nt)
        bnt[nt] = bias[n0 + wn * 64 + nt * 16 + col];
#pragma unroll
    for (int mt = 0; mt < 4; ++mt) {
        const int rowb = m0 + wm * 64 + mt * 16 + quad * 4;
#pragma unroll
        for (int nt = 0; nt < 4; ++nt) {
            const int cc = n0 + wn * 64 + nt * 16 + col;
#pragma unroll
            for (int r = 0; r < 4; ++r) {
                float v = acc[mt][nt][r] + bnt[nt];
                if (f16o)
                    ((_Float16*)Cv)[(size_t)(rowb + r) * 512 + cc] = (_Float16)v;
                else
                    ((float*)Cv)[(size_t)(rowb + r) * 512 + cc] = v;
            }
        }
    }
}

// ---------------------------------------------------------------------------
// Merged key+query projection: 5 groups. g<3: A=K16 (M=8192, 64 m-blocks);
// g>=3: A=Q16 (M=1024, m-blocks 0..7, rest exit). Grid: (64, 20).
// f16 outputs except V (g=2).
// ---------------------------------------------------------------------------
__global__ __launch_bounds__(256) void mfma_proj5(
    const _Float16* __restrict__ Akey, const _Float16* __restrict__ Aqry,
    const _Float16* __restrict__ Wt5,
    const float* __restrict__ b0, void* __restrict__ C0,
    const float* __restrict__ b1, void* __restrict__ C1,
    const float* __restrict__ b2, void* __restrict__ C2,
    const float* __restrict__ b3, void* __restrict__ C3,
    const float* __restrict__ b4, void* __restrict__ C4)
{
    __shared__ _Float16 As[128 * ASTR];
    __shared__ _Float16 Bs[128 * ASTR];
    const int g = blockIdx.y >> 2, nt128 = blockIdx.y & 3;
    const bool qry = g >= 3;
    if (qry && blockIdx.x >= 8) return;
    const _Float16* A16 = qry ? Aqry : Akey;
    const _Float16* Wt = Wt5 + (size_t)g * 262144;
    const float* bias = (g == 0) ? b0 : (g == 1) ? b1 : (g == 2) ? b2
                      : (g == 3) ? b3 : b4;
    void* Cv = (g == 0) ? C0 : (g == 1) ? C1 : (g == 2) ? C2
             : (g == 3) ? C3 : C4;
    const int f16o = (g == 2) ? 0 : 1;
    gemm_core(A16, Wt, As, Bs, blockIdx.x * 128, nt128 * 128, bias, Cv, f16o);
}

// ---------------------------------------------------------------------------
// Output projection (M=1024, 1 group, fp32 out). Grid: (8, 4).
// ---------------------------------------------------------------------------
__global__ __launch_bounds__(256) void mfma_proj_out(
    const _Float16* __restrict__ A16, const _Float16* __restrict__ Wt,
    const float* __restrict__ bias, float* __restrict__ C)
{
    __shared__ _Float16 As[128 * ASTR];
    __shared__ _Float16 Bs[128 * ASTR];
    gemm_core(A16, Wt, As, Bs, blockIdx.x * 128, blockIdx.y * 128, bias, C, 0);
}

// ---------------------------------------------------------------------------
// Energy via MFMA, both heads in one launch (direct-global frags, K=128).
// Grid: (kt=8, h=4, z=16); z<8: mono (b=z, +r, e_mono); z>=8: chunk.
// ---------------------------------------------------------------------------
__device__ __forceinline__ void load_frags_g(
    const _Float16* Ap, const _Float16* Bp, int kk, half8 a[4], half8 b[4])
{
#pragma unroll
    for (int t = 0; t < 4; ++t) {
        a[t] = *(const half8*)(Ap + (size_t)t * 16 * 512 + kk);
        b[t] = *(const half8*)(Bp + (size_t)t * 16 * 512 + kk);
    }
}

__global__ __launch_bounds__(256) void energy_mfma(
    const _Float16* __restrict__ Qm, const _Float16* __restrict__ Km,
    const _Float16* __restrict__ Qc, const _Float16* __restrict__ Kc,
    const int* __restrict__ mask, float* __restrict__ e_mono,
    float* __restrict__ e_chunk, const float* __restrict__ r_ptr)
{
    const int tid = threadIdx.x;
    const int lane = tid & 63, wave = tid >> 6;
    const int wm = wave >> 1, wn = wave & 1;
    const int col = lane & 15, quad = lane >> 4;
    const int kt0 = blockIdx.x * 128;
    const int h = blockIdx.y;
    const int z = blockIdx.z;
    const int b = z & 7;
    const bool mono = z < 8;
    const _Float16* Qp = mono ? Qm : Qc;
    const _Float16* Kp = mono ? Km : Kc;
    float* out = mono ? e_mono : e_chunk;
    const float rv = mono ? r_ptr[0] : 0.f;

    const _Float16* Ap = Qp + (size_t)(b * 128 + wm * 64 + col) * 512 + h * 128 + quad * 8;
    const _Float16* Bp = Kp + (size_t)(b * 1024 + kt0 + wn * 64 + col) * 512 + h * 128 + quad * 8;

    f32x4 acc[4][4];
#pragma unroll
    for (int mt = 0; mt < 4; ++mt)
#pragma unroll
        for (int nt = 0; nt < 4; ++nt) acc[mt][nt] = (f32x4)0.f;

    half8 ab[3][4], bb[3][4];
    load_frags_g(Ap, Bp, 0, ab[0], bb[0]);
    load_frags_g(Ap, Bp, 32, ab[1], bb[1]);
#pragma unroll
    for (int ks = 0; ks < 4; ++ks) {
        const int cur = ks % 3, nxt = (ks + 2) % 3;
        if (ks + 2 < 4)
            load_frags_g(Ap, Bp, (ks + 2) * 32, ab[nxt], bb[nxt]);
        mfma_step(ab[cur], bb[cur], acc);
    }

#pragma unroll
    for (int mt = 0; mt < 4; ++mt) {
        const int qb = wm * 64 + mt * 16 + quad * 4;
#pragma unroll
        for (int nt = 0; nt < 4; ++nt) {
            const int kc = kt0 + wn * 64 + nt * 16 + col;
#pragma unroll
            for (int r = 0; r < 4; ++r) {
                const int q = qb + r;
                float v = acc[mt][nt][r] * INV_SCALE + rv;
                int mv = mask[((size_t)b * 128 + q) * 1024 + kc];
                out[(((size_t)b * 4 + h) * 128 + q) * 1024 + kc] = mv ? v : NEG_INF;
            }
        }
    }
}

// ---------------------------------------------------------------------------
// transcend_row: (pcp, invcp) for one (b,h,q) row computed by one wave.
// ---------------------------------------------------------------------------
__device__ __forceinline__ void transcend_row(
    const float* __restrict__ Erow, int lane, float o_pcp[16], float o_inv[16])
{
    const float* E = Erow + lane * 16;
    float e[16];
    *(float4*)&e[0]  = *(const float4*)(E);
    *(float4*)&e[4]  = *(const float4*)(E + 4);
    *(float4*)&e[8]  = *(const float4*)(E + 8);
    *(float4*)&e[12] = *(const float4*)(E + 12);

    float p[16], l[16];
#pragma unroll
    for (int i = 0; i < 16; ++i) {
        p[i] = 1.f / (1.f + expf(-e[i]));
        l[i] = logf(fmaxf(1.f - p[i], EPS_MOCHA));
    }
    float incl[16];
    incl[0] = l[0];
#pragma unroll
    for (int i = 1; i < 16; ++i) incl[i] = incl[i - 1] + l[i];
    float total = incl[15];
    float x = wave_incl_scan(total);
    float base = x - total;  // exclusive across lanes
#pragma unroll
    for (int i = 0; i < 16; ++i) {
        float cl = base + (i ? incl[i - 1] : 0.f);
        float cp = expf(cl);
        o_pcp[i] = p[i] * cp;
        o_inv[i] = 1.f / fmaxf(cp, EPS_MOCHA);
    }
}

// ---------------------------------------------------------------------------
// alpha_pre: per row q (one wave, 4096 rows): compute pcp_q (stored) and
// G_q = pcp_{q-1} * invcp_q (q>0; recompute pcp_{q-1} from e row q-1).
// G_0 = delta(k==0) * invcp_0[0].
// ---------------------------------------------------------------------------
__global__ __launch_bounds__(256) void alpha_pre(
    const float* __restrict__ e_mono, float* __restrict__ G,
    float* __restrict__ pcp)
{
    const int tid = threadIdx.x;
    const int lane = tid & 63;
    const int row = blockIdx.x * 4 + (tid >> 6);
    const int q = row & 127;

    float pq[16], iq[16];
    transcend_row(e_mono + (size_t)row * 1024, lane, pq, iq);

    float* P = pcp + (size_t)row * 1024 + lane * 16;
    *(float4*)(P)      = *(float4*)&pq[0];
    *(float4*)(P + 4)  = *(float4*)&pq[4];
    *(float4*)(P + 8)  = *(float4*)&pq[8];
    *(float4*)(P + 12) = *(float4*)&pq[12];

    float g[16];
    if (q == 0) {
#pragma unroll
        for (int i = 0; i < 16; ++i) g[i] = 0.f;
        if (lane == 0) g[0] = iq[0];
    } else {
        float pm[16], im[16];
        transcend_row(e_mono + (size_t)(row - 1) * 1024, lane, pm, im);
#pragma unroll
        for (int i = 0; i < 16; ++i) g[i] = pm[i] * iq[i];
    }
    float* Gp = G + (size_t)row * 1024 + lane * 16;
    *(float4*)(Gp)      = *(float4*)&g[0];
    *(float4*)(Gp + 4)  = *(float4*)&g[4];
    *(float4*)(Gp + 8)  = *(float4*)&g[8];
    *(float4*)(Gp + 12) = *(float4*)&g[12];
}

// ---------------------------------------------------------------------------
// alpha_scan: one wave per (b,h), single 16MB stream (G), 8-deep prefetch
// (8x16 = 128 VGPR buffer), DPP wave scan.
// S_q = cumsum_k(G_q * S_{q-1}), S_{-1} = 1. (aw = pcp*S applied in beta.)
// ---------------------------------------------------------------------------
__global__ __launch_bounds__(64, 1) void alpha_scan(
    const float* __restrict__ G, float* __restrict__ S)
{
    const int lane = threadIdx.x;
    const int bh = blockIdx.x;
    const float* Gp = G + (size_t)bh * 131072 + lane * 16;
    float* Sp = S + (size_t)bh * 131072 + lane * 16;

    float bg[8][16];
#pragma unroll
    for (int s = 0; s < 8; ++s) {
        const float* Gq = Gp + (size_t)s * 1024;
        *(float4*)&bg[s][0]  = *(const float4*)(Gq);
        *(float4*)&bg[s][4]  = *(const float4*)(Gq + 4);
        *(float4*)&bg[s][8]  = *(const float4*)(Gq + 8);
        *(float4*)&bg[s][12] = *(const float4*)(Gq + 12);
    }

    float Sv[16];
#pragma unroll
    for (int i = 0; i < 16; ++i) Sv[i] = 1.f;  // S_{-1} = ones

    for (int q8 = 0; q8 < 128; q8 += 8) {
#pragma unroll
        for (int s = 0; s < 8; ++s) {
            const int q = q8 + s;
            float g[16];
#pragma unroll
            for (int i = 0; i < 16; ++i) g[i] = bg[s][i];
            if (q + 8 < 128) {  // refill slot s for q+8 (issues before chain)
                const float* Gq = Gp + (size_t)(q + 8) * 1024;
                *(float4*)&bg[s][0]  = *(const float4*)(Gq);
                *(float4*)&bg[s][4]  = *(const float4*)(Gq + 4);
                *(float4*)&bg[s][8]  = *(const float4*)(Gq + 8);
                *(float4*)&bg[s][12] = *(const float4*)(Gq + 12);
            }

            float incl[16];
            incl[0] = g[0] * Sv[0];
#pragma unroll
            for (int i = 1; i < 16; ++i)
                incl[i] = fmaf(g[i], Sv[i], incl[i - 1]);
            float total = incl[15];
            float x = wave_incl_scan(total);
            float base = x - total;  // exclusive across lanes
#pragma unroll
            for (int i = 0; i < 16; ++i) Sv[i] = base + incl[i];

            float* Sq = Sp + (size_t)q * 1024;
            *(float4*)(Sq)      = *(float4*)&Sv[0];
            *(float4*)(Sq + 4)  = *(float4*)&Sv[4];
            *(float4*)(Sq + 8)  = *(float4*)&Sv[8];
            *(float4*)(Sq + 12) = *(float4*)&Sv[12];
        }
    }
}

// ---------------------------------------------------------------------------
// Beta -> fp16. One block per (b,q); alpha = pcp*S reconstructed on load.
// LDS swizzle SW(k)=k+(k>>3). Grid: (q=128, b=8), 256 threads, 4 k each.
// ---------------------------------------------------------------------------
#define SW(k) ((k) + ((k) >> 3))

__global__ __launch_bounds__(256) void beta_kernel(
    const float* __restrict__ e_chunk, const float* __restrict__ pcp,
    const float* __restrict__ S, _Float16* __restrict__ beta)
{
    __shared__ float sm[SW(1023) + 1];
    __shared__ float tm[SW(1027) + 1];
    __shared__ float red[4];
    const int q = blockIdx.x, b = blockIdx.y;
    const int tid = threadIdx.x;
    const int lane = tid & 63, wid = tid >> 6;
    const int k4 = tid * 4;

    float av[4][4];
#pragma unroll
    for (int hm = 0; hm < 4; ++hm) {
        const size_t off = (((size_t)b * 4 + hm) * 128 + q) * 1024 + k4;
        float4 pv = *(const float4*)(pcp + off);
        float4 sv = *(const float4*)(S + off);
        av[hm][0] = pv.x * sv.x;
        av[hm][1] = pv.y * sv.y;
        av[hm][2] = pv.z * sv.z;
        av[hm][3] = pv.w * sv.w;
    }

    if (tid < 4) tm[SW(1024 + tid)] = 0.f;  // fwd-window zero pad (set once)

    for (int hc = 0; hc < 4; ++hc) {
        float4 ev = *(const float4*)(e_chunk + (((size_t)b * 4 + hc) * 128 + q) * 1024 + k4);
        float e[4] = {ev.x, ev.y, ev.z, ev.w};

        float mx = fmaxf(fmaxf(e[0], e[1]), fmaxf(e[2], e[3]));
#pragma unroll
        for (int off = 32; off >= 1; off >>= 1)
            mx = fmaxf(mx, __shfl_xor(mx, off, 64));
        if (lane == 0) red[wid] = mx;
        __syncthreads();
        mx = fmaxf(fmaxf(red[0], red[1]), fmaxf(red[2], red[3]));

        float sx[4];
#pragma unroll
        for (int i = 0; i < 4; ++i) {
            sx[i] = fmaxf(expf(e[i] - mx), 1e-5f);
            sm[SW(k4 + i)] = sx[i];
        }
        __syncthreads();

        float den[4];
#pragma unroll
        for (int i = 0; i < 4; ++i) {
            int k = k4 + i;
            float d = sm[SW(k)];
            if (k >= 1) d += sm[SW(k - 1)];
            if (k >= 2) d += sm[SW(k - 2)];
            if (k >= 3) d += sm[SW(k - 3)];
            den[i] = d;
        }

#pragma unroll
        for (int hm = 0; hm < 4; ++hm) {
            float t[4] = {av[hm][0] / den[0], av[hm][1] / den[1],
                          av[hm][2] / den[2], av[hm][3] / den[3]};
#pragma unroll
            for (int i = 0; i < 4; ++i) tm[SW(k4 + i)] = t[i];
            __syncthreads();
            float o[4];
#pragma unroll
            for (int i = 0; i < 4; ++i) {
                int k = k4 + i;
                float ms = tm[SW(k)] + tm[SW(k + 1)] + tm[SW(k + 2)] + tm[SW(k + 3)];
                o[i] = sx[i] * ms;
            }
            _Float16* Brow = beta + (((size_t)b * 16 + hm * 4 + hc) * 128 + q) * 1024;
            half4v hv = {(_Float16)o[0], (_Float16)o[1], (_Float16)o[2], (_Float16)o[3]};
            *(half4v*)(Brow + k4) = hv;
            __syncthreads();
        }
    }
}

// ---------------------------------------------------------------------------
// Context: cv16[b,q,h*32+d] = (fp16) sum_k beta16[b,h,q,k] * V[b,k,h*32+d]
// ---------------------------------------------------------------------------
__global__ __launch_bounds__(256) void context_kernel(
    const _Float16* __restrict__ beta, const float* __restrict__ V,
    _Float16* __restrict__ cv16)
{
    __shared__ float bS[32][64];
    __shared__ float vS[32][32];
    const int qh = blockIdx.x, h = blockIdx.y, b = blockIdx.z;
    const int tid = threadIdx.x;
    const int ty = tid >> 3, tx = tid & 7;
    const int q0 = qh * 64;

    const _Float16* Bbase = beta + (((size_t)b * 16 + h) * 128 + q0) * 1024;
    const float* Vbase = V + (size_t)b * 1024 * 512 + h * 32;

    float acc[2][4];
#pragma unroll
    for (int i = 0; i < 2; ++i)
#pragma unroll
        for (int j = 0; j < 4; ++j) acc[i][j] = 0.f;

    for (int k0 = 0; k0 < 1024; k0 += 32) {
        {
            int r = tid >> 2, c = tid & 3;
            half8 v = *(const half8*)(Bbase + (size_t)r * 1024 + k0 + c * 8);
#pragma unroll
            for (int j = 0; j < 8; ++j) bS[c * 8 + j][r] = (float)v[j];
        }
        {
            int kk = tid >> 3, c = tid & 7;
            float4 v = *(const float4*)(Vbase + (size_t)(k0 + kk) * 512 + c * 4);
            *(float4*)&vS[kk][c * 4] = v;
        }
        __syncthreads();
#pragma unroll
        for (int kk = 0; kk < 32; ++kk) {
            float a0 = bS[kk][ty * 2], a1 = bS[kk][ty * 2 + 1];
            float bb[4];
            *(float4*)bb = *(const float4*)&vS[kk][tx * 4];
#pragma unroll
            for (int j = 0; j < 4; ++j) {
                acc[0][j] = fmaf(a0, bb[j], acc[0][j]);
                acc[1][j] = fmaf(a1, bb[j], acc[1][j]);
            }
        }
        __syncthreads();
    }
#pragma unroll
    for (int i = 0; i < 2; ++i) {
        _Float16* Cp = cv16 + ((size_t)b * 128 + q0 + ty * 2 + i) * 512 + h * 32 + tx * 4;
        half4v hv = {(_Float16)acc[i][0], (_Float16)acc[i][1],
                     (_Float16)acc[i][2], (_Float16)acc[i][3]};
        *(half4v*)Cp = hv;
    }
}

// ---------------------------------------------------------------------------
extern "C" void kernel_launch(void* const* d_in, const int* in_sizes, int n_in,
                              void* d_out, int out_size, void* d_ws, size_t ws_size,
                              hipStream_t stream)
{
    const float* key_x   = (const float*)d_in[0];
    const float* query_x = (const float*)d_in[1];
    const int*   mask    = (const int*)d_in[2];
    const float* wk_m = (const float*)d_in[3];
    const float* bk_m = (const float*)d_in[4];
    const float* wq_m = (const float*)d_in[5];
    const float* bq_m = (const float*)d_in[6];
    const float* r    = (const float*)d_in[7];
    const float* wk_c = (const float*)d_in[8];
    const float* bk_c = (const float*)d_in[9];
    const float* wq_c = (const float*)d_in[10];
    const float* bq_c = (const float*)d_in[11];
    const float* wv   = (const float*)d_in[12];
    const float* bv   = (const float*)d_in[13];
    const float* wo   = (const float*)d_in[14];
    const float* bo   = (const float*)d_in[15];
    float* out = (float*)d_out;

    float* ws = (float*)d_ws;
    _Float16* hws = (_Float16*)d_ws;
    const size_t MEGF = 1024 * 1024;
    // Float-unit layout (fp16 offsets are 2x float offsets):
    //  phase A: K16 f[0,2), Q16 f[4,4.25), Wt5 f[4.5,5.25),
    //           Km16 f[6,8), Kc16 f[8,10), Qm16 f[10,10.125),
    //           Qc16 f[10.25,10.375), e_mono f[11,15), e_chunk f[15,19),
    //           V f[19,23), Wt_wo f[27.5,27.625)
    //  phase B (alpha): G f[0,4) (K16 + free f[2,4)); pcp f[8,10) (dead Kc16);
    //           S f[23,27). e_mono NOT overwritten (pre reads rows q, q-1).
    //  phase C: beta16 f[0,8) (G/Q16/Wt5/Km16 dead; pcp f[8,10) preserved),
    //           cv16 f[27.75,28). Peak 28 MEGF.
    _Float16* K16   = hws;                          // f 0
    _Float16* Q16   = hws + 8 * MEGF;               // f 4
    _Float16* Wt5   = hws + 9 * MEGF;               // f 4.5
    _Float16* Km16  = hws + 12 * MEGF;              // f 6
    _Float16* Kc16  = hws + 16 * MEGF;              // f 8
    _Float16* Qm16  = hws + 20 * MEGF;              // f 10
    _Float16* Qc16  = hws + 20 * MEGF + MEGF / 2;   // f 10.25
    float* e_mono  = ws + 11 * MEGF;
    float* e_chunk = ws + 15 * MEGF;
    float* V       = ws + 19 * MEGF;
    float* G       = ws;                            // f 0 (over dead K16)
    float* pcp     = ws + 8 * MEGF;                 // f 8 (over dead Kc16)
    float* S       = ws + 23 * MEGF;                // f 23
    _Float16* beta16 = hws;                         // f 0 (phase C overlay)
    _Float16* Wt_wo = hws + 55 * MEGF;              // f 27.5
    _Float16* cv16  = hws + 55 * MEGF + MEGF / 2;   // f 27.75

    // 0) merged prep: cvt key/query + pack 6 weights
    prep_kernel<<<dim3(4992), 256, 0, stream>>>(
        key_x, query_x, wk_m, wk_c, wv, wq_m, wq_c, wo,
        K16, Q16, Wt5, Wt_wo);
    // 1) all five projections in one launch
    mfma_proj5<<<dim3(64, 20), 256, 0, stream>>>(
        K16, Q16, Wt5,
        bk_m, Km16, bk_c, Kc16, bv, V, bq_m, Qm16, bq_c, Qc16);
    // 2) both energies in one launch
    energy_mfma<<<dim3(8, 4, 16), 256, 0, stream>>>(
        Qm16, Km16, Qc16, Kc16, mask, e_mono, e_chunk, r);
    // 3) monotonic alpha: G/pcp precompute + single-stream DPP scan
    alpha_pre<<<dim3(1024), 256, 0, stream>>>(e_mono, G, pcp);
    alpha_scan<<<dim3(32), 64, 0, stream>>>(G, S);
    // 4) chunkwise beta (fp16 out), one block per (b,q); aw = pcp*S inline
    beta_kernel<<<dim3(128, 8), 256, 0, stream>>>(e_chunk, pcp, S, beta16);
    // 5) context vectors -> cv16 directly
    context_kernel<<<dim3(2, 16, 8), 256, 0, stream>>>(beta16, V, cv16);
    // 6) output projection (M=1024, fp32 out)
    mfma_proj_out<<<dim3(8, 4), 256, 0, stream>>>(cv16, Wt_wo, bo, out);
}